// Round 3
// baseline (1052.254 us; speedup 1.0000x reference)
//
#include <hip/hip_runtime.h>

// Fused multi-graph GCN inference (N=320k nodes, E=5.12M edges, features 1->16->16->8->1).
// Algebra: x is [N,1] so layer-1 collapses to a scalar per node:
//   p[v] = x[v]*dinv[v];  s[v] = dinv[v]*(sum_{e:dst=v} p[src[e]] + p[v])
//   h1[v][j] = relu(W1[j]*s[v] + b1[j]);  contribution to layer-2 agg = h1*dinv[v]
// Aggregation commutes with @W2, so W2/b2/fc1/fc2 apply only to the ~32k gathered rows.
// Layer-2 scatter is filtered via slot[] (compact row index for needed dst nodes, -1 otherwise).
//
// ws layout (4-byte units): [deg->dinv: N][t1->s: N][p: N][slot: N ints][aggc: 16*M]
// total = (4N + 16M)*4 bytes ~= 7.2 MB.

__global__ void k_fill_f(float* __restrict__ w, float v, int n) {
    int i = blockIdx.x * blockDim.x + threadIdx.x;
    if (i < n) w[i] = v;
}
__global__ void k_fill_i(int* __restrict__ w, int v, int n) {
    int i = blockIdx.x * blockDim.x + threadIdx.x;
    if (i < n) w[i] = v;
}

__global__ void k_mark(const int* __restrict__ gene_idx, int* __restrict__ slot,
                       int G, int M, int npg, int N) {
    int i = blockIdx.x * blockDim.x + threadIdx.x;
    if (i >= M) return;
    int g = i % G;
    int rep = i / G;
    int gi = gene_idx[g];
    int node = gi + rep * npg;
    if ((unsigned)node < (unsigned)N) slot[node] = i;  // racing writers: any winner is consistent
}

__global__ void k_deg(const int* __restrict__ dst, float* __restrict__ deg, int E, int N) {
    int e = blockIdx.x * blockDim.x + threadIdx.x;
    if (e >= E) return;
    int d = dst[e];
    if ((unsigned)d < (unsigned)N) atomicAdd(&deg[d], 1.0f);
}

__global__ void k_dinv_p(const float* __restrict__ x, float* __restrict__ degv,
                         float* __restrict__ p, int N) {
    int v = blockIdx.x * blockDim.x + threadIdx.x;
    if (v < N) {
        float d = degv[v] + 1.0f;          // + self-loop; always >= 1
        float di = rsqrtf(d);
        degv[v] = di;                      // deg array becomes dinv in-place
        p[v] = x[v] * di;
    }
}

__global__ void k_scatter1(const int* __restrict__ src, const int* __restrict__ dst,
                           const float* __restrict__ p, float* __restrict__ t1, int E, int N) {
    int e = blockIdx.x * blockDim.x + threadIdx.x;
    if (e >= E) return;
    int s = src[e];
    int d = dst[e];
    if ((unsigned)s < (unsigned)N && (unsigned)d < (unsigned)N)
        atomicAdd(&t1[d], p[s]);
}

// t1[v] <- s[v] = dinv[v]*(t1[v] + p[v])
__global__ void k_s(const float* __restrict__ p, const float* __restrict__ dinv,
                    float* __restrict__ t1, int N) {
    int v = blockIdx.x * blockDim.x + threadIdx.x;
    if (v < N) t1[v] = dinv[v] * (t1[v] + p[v]);
}

// Layer-2 scatter, filtered: only edges whose dst has a slot contribute.
__global__ void k_scatter2(const int* __restrict__ src, const int* __restrict__ dst,
                           const float* __restrict__ s, const float* __restrict__ dinv,
                           const int* __restrict__ slot,
                           const float* __restrict__ W1, const float* __restrict__ b1,
                           float* __restrict__ aggc, int E, int N) {
    int e = blockIdx.x * blockDim.x + threadIdx.x;
    if (e >= E) return;
    int d = dst[e];
    if ((unsigned)d >= (unsigned)N) return;
    int sl = slot[d];
    if (sl < 0) return;
    int sv = src[e];
    if ((unsigned)sv >= (unsigned)N) return;
    float sval = s[sv];
    float di = dinv[sv];
    float* arow = aggc + (size_t)sl * 16;
#pragma unroll
    for (int j = 0; j < 16; j++) {
        float h = fmaxf(fmaf(W1[j], sval, b1[j]), 0.0f) * di;
        atomicAdd(&arow[j], h);
    }
}

// Head: per output row, finish layer-2 (dinv*(agg+qself))@W2+b2, relu, fc1+relu, fc2.
__global__ void k_final(const float* __restrict__ aggc, const float* __restrict__ s,
                        const float* __restrict__ dinv,
                        const int* __restrict__ gene_idx, const int* __restrict__ slot,
                        const float* __restrict__ W1, const float* __restrict__ b1,
                        const float* __restrict__ W2, const float* __restrict__ b2,
                        const float* __restrict__ f1W, const float* __restrict__ f1b,
                        const float* __restrict__ f2W, const float* __restrict__ f2b,
                        float* __restrict__ out, int G, int M, int npg, int N) {
    __shared__ float sW1[16], sb1[16], sW2[256], sb2[16], sf1[128], sf1b[8], sf2[8], sf2b[1];
    for (int i = threadIdx.x; i < 256; i += blockDim.x) sW2[i] = W2[i];
    for (int i = threadIdx.x; i < 128; i += blockDim.x) sf1[i] = f1W[i];
    if (threadIdx.x < 16) { sW1[threadIdx.x] = W1[threadIdx.x]; sb1[threadIdx.x] = b1[threadIdx.x]; sb2[threadIdx.x] = b2[threadIdx.x]; }
    if (threadIdx.x < 8)  { sf1b[threadIdx.x] = f1b[threadIdx.x]; sf2[threadIdx.x] = f2W[threadIdx.x]; }
    if (threadIdx.x == 0) sf2b[0] = f2b[0];
    __syncthreads();

    int i = blockIdx.x * blockDim.x + threadIdx.x;
    if (i >= M) return;
    int g = i % G;
    int rep = i / G;
    int node = gene_idx[g] + rep * npg;
    if ((unsigned)node >= (unsigned)N) { out[i] = 0.0f; return; }
    int sl = slot[node];

    float di = dinv[node];
    float sval = s[node];
    const float* ar = aggc + (size_t)(sl < 0 ? 0 : sl) * 16;
    float a[16];
#pragma unroll
    for (int j = 0; j < 16; j++) {
        float qself = fmaxf(fmaf(sW1[j], sval, sb1[j]), 0.0f) * di;  // self-loop term
        float agg = (sl < 0) ? 0.0f : ar[j];
        a[j] = di * (agg + qself);
    }
    float h2[16];
#pragma unroll
    for (int j = 0; j < 16; j++) {
        float acc = sb2[j];
#pragma unroll
        for (int k = 0; k < 16; k++) acc = fmaf(a[k], sW2[k * 16 + j], acc);
        h2[j] = fmaxf(acc, 0.0f);
    }
    float f1[8];
#pragma unroll
    for (int j = 0; j < 8; j++) {
        float acc = sf1b[j];
#pragma unroll
        for (int k = 0; k < 16; k++) acc = fmaf(h2[k], sf1[k * 8 + j], acc);
        f1[j] = fmaxf(acc, 0.0f);
    }
    float o = sf2b[0];
#pragma unroll
    for (int k = 0; k < 8; k++) o = fmaf(f1[k], sf2[k], o);
    out[i] = o;
}

extern "C" void kernel_launch(void* const* d_in, const int* in_sizes, int n_in,
                              void* d_out, int out_size, void* d_ws, size_t ws_size,
                              hipStream_t stream) {
    const float* x        = (const float*)d_in[0];
    const int*   ei       = (const int*)d_in[1];     // int per harness convention
    const int*   gene_idx = (const int*)d_in[3];
    const float* W1  = (const float*)d_in[5];
    const float* b1  = (const float*)d_in[6];
    const float* W2  = (const float*)d_in[7];
    const float* b2  = (const float*)d_in[8];
    const float* f1W = (const float*)d_in[9];
    const float* f1b = (const float*)d_in[10];
    const float* f2W = (const float*)d_in[11];
    const float* f2b = (const float*)d_in[12];
    float* out = (float*)d_out;

    int N = in_sizes[0];       // 320000
    int E = in_sizes[1] / 2;   // 5120000
    int M = in_sizes[2];       // 32000 (= reps * G)
    int G = in_sizes[3];       // 1000
    int npg = (int)(((long long)N * (long long)G) / (long long)M);  // N / num_graphs

    const int* src = ei;
    const int* dst = ei + E;

    float* ws   = (float*)d_ws;
    float* deg  = ws;                       // N (becomes dinv)
    float* t1   = ws + (size_t)N;           // N (becomes s)
    float* p    = ws + 2 * (size_t)N;       // N
    int*   slot = (int*)(ws + 3 * (size_t)N); // N ints
    float* aggc = ws + 4 * (size_t)N;       // 16*M

    const int tb = 256;
    k_fill_f<<<(2 * N + tb - 1) / tb, tb, 0, stream>>>(deg, 0.0f, 2 * N);        // deg + t1
    k_fill_i<<<(N + tb - 1) / tb, tb, 0, stream>>>(slot, -1, N);
    k_fill_f<<<(16 * M + tb - 1) / tb, tb, 0, stream>>>(aggc, 0.0f, 16 * M);

    k_mark<<<(M + tb - 1) / tb, tb, 0, stream>>>(gene_idx, slot, G, M, npg, N);
    k_deg<<<(E + tb - 1) / tb, tb, 0, stream>>>(dst, deg, E, N);
    k_dinv_p<<<(N + tb - 1) / tb, tb, 0, stream>>>(x, deg, p, N);
    k_scatter1<<<(E + tb - 1) / tb, tb, 0, stream>>>(src, dst, p, t1, E, N);
    k_s<<<(N + tb - 1) / tb, tb, 0, stream>>>(p, deg, t1, N);
    k_scatter2<<<(E + tb - 1) / tb, tb, 0, stream>>>(src, dst, t1, deg, slot, W1, b1, aggc, E, N);
    k_final<<<(M + tb - 1) / tb, tb, 0, stream>>>(aggc, t1, deg, gene_idx, slot,
                                                  W1, b1, W2, b2, f1W, f1b, f2W, f2b,
                                                  out, G, M, npg, N);
}

// Round 4
// 689.397 us; speedup vs baseline: 1.5263x; 1.5263x over previous
//
#include <hip/hip_runtime.h>

// Fused multi-graph GCN inference (N=320k, E=5.12M, features 1->16->16->8->1).
// Layer-1 collapses to a scalar per node (x is [N,1]).
// Layer-2 scatter uses the relu-threshold bucket trick: per edge only TWO atomics
// (sum of s*dinv and sum of dinv into the bucket of s's threshold interval);
// the 16 aggregated features are reconstructed per destination afterwards:
//   agg_j = W1[j]*Sum_active(s*dinv) + b1[j]*Sum_active(dinv).
//
// ws layout (4B units): [deg->dinv: N][t1->s: N][p: N][slot: N ints]
//                       [aggb: 34*M][bnd: 16 f][prepI: 18 ints]

#define MAXB 17  // max buckets (16 thresholds + 1)

__global__ void k_fill_f(float* __restrict__ w, float v, int n) {
    int i = blockIdx.x * blockDim.x + threadIdx.x;
    if (i < n) w[i] = v;
}
__global__ void k_fill_i(int* __restrict__ w, int v, int n) {
    int i = blockIdx.x * blockDim.x + threadIdx.x;
    if (i < n) w[i] = v;
}

// Single-thread prep: sorted unique thresholds + per-bucket active-feature masks.
__global__ void k_prep(const float* __restrict__ W1, const float* __restrict__ b1,
                       float* __restrict__ bnd, int* __restrict__ prepI) {
    if (threadIdx.x != 0 || blockIdx.x != 0) return;
    float t[16]; int type[16]; int pos[16];
    float thr[16]; int nt = 0;
    for (int j = 0; j < 16; j++) {
        float W = W1[j], B = b1[j];
        if (W > 0.f)      { type[j] = 0; t[j] = -B / W; }   // active iff s > t
        else if (W < 0.f) { type[j] = 1; t[j] = -B / W; }   // active iff s < t
        else              { type[j] = (B > 0.f) ? 2 : 3; t[j] = 0.f; } // always / never
    }
    for (int j = 0; j < 16; j++) {
        if (type[j] > 1) continue;
        float v = t[j];
        int k = 0; while (k < nt && thr[k] < v) k++;
        if (!(k < nt && thr[k] == v)) {
            for (int m = nt; m > k; m--) thr[m] = thr[m - 1];
            thr[k] = v; nt++;
        }
    }
    int K = nt + 1;
    for (int j = 0; j < 16; j++) {
        if (type[j] <= 1) { int k = 0; while (thr[k] != t[j]) k++; pos[j] = k; }
        else pos[j] = 0;
    }
    for (int k = 0; k < 16; k++) bnd[k] = (k < nt) ? thr[k] : 3.4e38f;
    prepI[0] = K;
    for (int k = 0; k < K; k++) {
        unsigned m = 0;
        for (int j = 0; j < 16; j++) {
            bool act;
            if (type[j] == 0)      act = (k >= pos[j] + 1);
            else if (type[j] == 1) act = (k <= pos[j]);
            else                   act = (type[j] == 2);
            if (act) m |= (1u << j);
        }
        prepI[1 + k] = (int)m;
    }
}

__global__ void k_mark(const int* __restrict__ gene_idx, int* __restrict__ slot,
                       int G, int M, int npg, int N) {
    int i = blockIdx.x * blockDim.x + threadIdx.x;
    if (i >= M) return;
    int node = gene_idx[i % G] + (i / G) * npg;
    if ((unsigned)node < (unsigned)N) slot[node] = i;  // racing writers: any winner consistent
}

__global__ void k_deg(const int* __restrict__ dst, float* __restrict__ deg, int E, int N) {
    int e = blockIdx.x * blockDim.x + threadIdx.x;
    if (e >= E) return;
    int d = dst[e];
    if ((unsigned)d < (unsigned)N) atomicAdd(&deg[d], 1.0f);
}

__global__ void k_dinv_p(const float* __restrict__ x, float* __restrict__ degv,
                         float* __restrict__ p, int N) {
    int v = blockIdx.x * blockDim.x + threadIdx.x;
    if (v < N) {
        float di = rsqrtf(degv[v] + 1.0f);  // + self-loop; >= 1
        degv[v] = di;                       // deg -> dinv in place
        p[v] = x[v] * di;
    }
}

__global__ void k_scatter1(const int* __restrict__ src, const int* __restrict__ dst,
                           const float* __restrict__ p, float* __restrict__ t1, int E, int N) {
    int e = blockIdx.x * blockDim.x + threadIdx.x;
    if (e >= E) return;
    int s = src[e];
    int d = dst[e];
    if ((unsigned)s < (unsigned)N && (unsigned)d < (unsigned)N)
        atomicAdd(&t1[d], p[s]);
}

// t1[v] <- s[v] = dinv[v]*(t1[v] + p[v])
__global__ void k_s(const float* __restrict__ p, const float* __restrict__ dinv,
                    float* __restrict__ t1, int N) {
    int v = blockIdx.x * blockDim.x + threadIdx.x;
    if (v < N) t1[v] = dinv[v] * (t1[v] + p[v]);
}

// Layer-2 scatter: per surviving edge, 2 atomics into the bucket of s[src]'s interval.
__global__ void k_scatter2(const int* __restrict__ src, const int* __restrict__ dst,
                           const float* __restrict__ s, const float* __restrict__ dinv,
                           const int* __restrict__ slot,
                           const float* __restrict__ bnd, const int* __restrict__ prepI,
                           float* __restrict__ aggb, int E, int N) {
    __shared__ float sB[16];
    __shared__ int sT;
    if (threadIdx.x == 0) sT = prepI[0] - 1;
    if (threadIdx.x < 16) sB[threadIdx.x] = bnd[threadIdx.x];
    __syncthreads();
    int e = blockIdx.x * blockDim.x + threadIdx.x;
    if (e >= E) return;
    int d = dst[e];
    if ((unsigned)d >= (unsigned)N) return;
    int sl = slot[d];
    if (sl < 0) return;
    int sv = src[e];
    if ((unsigned)sv >= (unsigned)N) return;
    float sval = s[sv];
    float di = dinv[sv];
    int T = sT;
    int b = 0;
    for (int i = 0; i < T; i++) b += (sval > sB[i]) ? 1 : 0;
    float* row = aggb + (size_t)sl * (2 * MAXB) + 2 * b;
    atomicAdd(row, sval * di);
    atomicAdd(row + 1, di);
}

// Head: reconstruct agg features from buckets, add self term, W2+relu, fc1+relu, fc2.
__global__ void k_final(const float* __restrict__ aggb, const float* __restrict__ s,
                        const float* __restrict__ dinv,
                        const int* __restrict__ gene_idx, const int* __restrict__ slot,
                        const int* __restrict__ prepI,
                        const float* __restrict__ W1, const float* __restrict__ b1,
                        const float* __restrict__ W2, const float* __restrict__ b2,
                        const float* __restrict__ f1W, const float* __restrict__ f1b,
                        const float* __restrict__ f2W, const float* __restrict__ f2b,
                        float* __restrict__ out, int G, int M, int npg, int N) {
    __shared__ float sW1[16], sb1[16], sW2[256], sb2[16], sf1[128], sf1b[8], sf2[8], sf2b[1];
    __shared__ int sMask[MAXB], sK;
    for (int i = threadIdx.x; i < 256; i += blockDim.x) sW2[i] = W2[i];
    for (int i = threadIdx.x; i < 128; i += blockDim.x) sf1[i] = f1W[i];
    if (threadIdx.x < 16) { sW1[threadIdx.x] = W1[threadIdx.x]; sb1[threadIdx.x] = b1[threadIdx.x]; sb2[threadIdx.x] = b2[threadIdx.x]; }
    if (threadIdx.x < 8)  { sf1b[threadIdx.x] = f1b[threadIdx.x]; sf2[threadIdx.x] = f2W[threadIdx.x]; }
    if (threadIdx.x == 0) { sf2b[0] = f2b[0]; sK = prepI[0]; }
    if (threadIdx.x < MAXB) sMask[threadIdx.x] = prepI[1 + threadIdx.x];
    __syncthreads();

    int i = blockIdx.x * blockDim.x + threadIdx.x;
    if (i >= M) return;
    int node = gene_idx[i % G] + (i / G) * npg;
    if ((unsigned)node >= (unsigned)N) { out[i] = 0.0f; return; }
    int sl = slot[node];

    float di = dinv[node];
    float sval = s[node];
    int K = sK;

    float bu[MAXB], bw[MAXB];
    if (sl >= 0) {
        const float* row = aggb + (size_t)sl * (2 * MAXB);
        for (int k = 0; k < K; k++) { bu[k] = row[2 * k]; bw[k] = row[2 * k + 1]; }
    } else {
        for (int k = 0; k < K; k++) { bu[k] = 0.f; bw[k] = 0.f; }
    }

    float a[16];
#pragma unroll
    for (int j = 0; j < 16; j++) {
        float Su = 0.f, Sw = 0.f;
        for (int k = 0; k < K; k++) {
            if ((sMask[k] >> j) & 1) { Su += bu[k]; Sw += bw[k]; }
        }
        float aggj = sW1[j] * Su + sb1[j] * Sw;                       // neighbor term
        float qself = fmaxf(fmaf(sW1[j], sval, sb1[j]), 0.0f) * di;   // self-loop term
        a[j] = di * (aggj + qself);
    }
    float h2[16];
#pragma unroll
    for (int j = 0; j < 16; j++) {
        float acc = sb2[j];
#pragma unroll
        for (int k = 0; k < 16; k++) acc = fmaf(a[k], sW2[k * 16 + j], acc);
        h2[j] = fmaxf(acc, 0.0f);
    }
    float f1[8];
#pragma unroll
    for (int j = 0; j < 8; j++) {
        float acc = sf1b[j];
#pragma unroll
        for (int k = 0; k < 16; k++) acc = fmaf(h2[k], sf1[k * 8 + j], acc);
        f1[j] = fmaxf(acc, 0.0f);
    }
    float o = sf2b[0];
#pragma unroll
    for (int k = 0; k < 8; k++) o = fmaf(f1[k], sf2[k], o);
    out[i] = o;
}

extern "C" void kernel_launch(void* const* d_in, const int* in_sizes, int n_in,
                              void* d_out, int out_size, void* d_ws, size_t ws_size,
                              hipStream_t stream) {
    const float* x        = (const float*)d_in[0];
    const int*   ei       = (const int*)d_in[1];
    const int*   gene_idx = (const int*)d_in[3];
    const float* W1  = (const float*)d_in[5];
    const float* b1  = (const float*)d_in[6];
    const float* W2  = (const float*)d_in[7];
    const float* b2  = (const float*)d_in[8];
    const float* f1W = (const float*)d_in[9];
    const float* f1b = (const float*)d_in[10];
    const float* f2W = (const float*)d_in[11];
    const float* f2b = (const float*)d_in[12];
    float* out = (float*)d_out;

    int N = in_sizes[0];       // 320000
    int E = in_sizes[1] / 2;   // 5120000
    int M = in_sizes[2];       // 32000 (= reps * G)
    int G = in_sizes[3];       // 1000
    int npg = (int)(((long long)N * (long long)G) / (long long)M);  // N / num_graphs

    const int* src = ei;
    const int* dst = ei + E;

    float* ws    = (float*)d_ws;
    float* deg   = ws;                         // N (becomes dinv)
    float* t1    = ws + (size_t)N;             // N (becomes s)
    float* p     = ws + 2 * (size_t)N;         // N
    int*   slot  = (int*)(ws + 3 * (size_t)N); // N ints
    float* aggb  = ws + 4 * (size_t)N;         // 2*MAXB*M
    float* bnd   = aggb + (size_t)2 * MAXB * M; // 16
    int*   prepI = (int*)(bnd + 16);            // 18 ints

    const int tb = 256;
    k_fill_f<<<(2 * N + tb - 1) / tb, tb, 0, stream>>>(deg, 0.0f, 2 * N);  // deg + t1
    k_fill_i<<<(N + tb - 1) / tb, tb, 0, stream>>>(slot, -1, N);
    k_fill_f<<<(2 * MAXB * M + tb - 1) / tb, tb, 0, stream>>>(aggb, 0.0f, 2 * MAXB * M);

    k_prep<<<1, 64, 0, stream>>>(W1, b1, bnd, prepI);
    k_mark<<<(M + tb - 1) / tb, tb, 0, stream>>>(gene_idx, slot, G, M, npg, N);
    k_deg<<<(E + tb - 1) / tb, tb, 0, stream>>>(dst, deg, E, N);
    k_dinv_p<<<(N + tb - 1) / tb, tb, 0, stream>>>(x, deg, p, N);
    k_scatter1<<<(E + tb - 1) / tb, tb, 0, stream>>>(src, dst, p, t1, E, N);
    k_s<<<(N + tb - 1) / tb, tb, 0, stream>>>(p, deg, t1, N);
    k_scatter2<<<(E + tb - 1) / tb, tb, 0, stream>>>(src, dst, t1, deg, slot,
                                                     bnd, prepI, aggb, E, N);
    k_final<<<(M + tb - 1) / tb, tb, 0, stream>>>(aggb, t1, deg, gene_idx, slot, prepI,
                                                  W1, b1, W2, b2, f1W, f1b, f2W, f2b,
                                                  out, G, M, npg, N);
}

// Round 6
// 354.548 us; speedup vs baseline: 2.9679x; 1.9444x over previous
//
#include <hip/hip_runtime.h>

// Fused multi-graph GCN inference (N=320k, E=5.12M, features 1->16->16->8->1).
// Layer-1 collapses to a scalar per node (x is [N,1]); layer-2 uses the
// relu-threshold bucket trick (agg_j = W1[j]*Sum_act(s*dinv) + b1[j]*Sum_act(dinv)).
// Counting-sort edges by dst-range (1024 nodes/range) so all per-edge
// aggregation happens in LDS; global f32 atomics eliminated.
// R5 bug: histG fill launched with 1 block (256 threads) for R=313 counters ->
// poisoned counters -> garbage scan bases -> OOB bucket stores -> abort. Fixed.

#define MAXB 17          // max relu buckets (16 thresholds + 1)
#define RS_BITS 10
#define RS (1 << RS_BITS)        // nodes per range
#define SRC_BITS 19              // N must be < 2^19
#define SRC_MASK ((1u << SRC_BITS) - 1u)
#define EPT 16                   // edges per thread in k_bucket (tile = 256*EPT)
#define TILE (256 * EPT)

__global__ void k_fill_f(float* __restrict__ w, float v, int n) {
    int i = blockIdx.x * blockDim.x + threadIdx.x;
    if (i < n) w[i] = v;
}
__global__ void k_fill_i(int* __restrict__ w, int v, int n) {
    int i = blockIdx.x * blockDim.x + threadIdx.x;
    if (i < n) w[i] = v;
}

// Single-thread prep: sorted unique relu thresholds + per-bucket active-feature masks.
__global__ void k_prep(const float* __restrict__ W1, const float* __restrict__ b1,
                       float* __restrict__ bnd, int* __restrict__ prepI) {
    if (threadIdx.x != 0 || blockIdx.x != 0) return;
    float t[16]; int type[16]; int pos[16];
    float thr[16]; int nt = 0;
    for (int j = 0; j < 16; j++) {
        float W = W1[j], B = b1[j];
        if (W > 0.f)      { type[j] = 0; t[j] = -B / W; }   // active iff s > t
        else if (W < 0.f) { type[j] = 1; t[j] = -B / W; }   // active iff s < t
        else              { type[j] = (B > 0.f) ? 2 : 3; t[j] = 0.f; }
    }
    for (int j = 0; j < 16; j++) {
        if (type[j] > 1) continue;
        float v = t[j];
        int k = 0; while (k < nt && thr[k] < v) k++;
        if (!(k < nt && thr[k] == v)) {
            for (int m = nt; m > k; m--) thr[m] = thr[m - 1];
            thr[k] = v; nt++;
        }
    }
    int K = nt + 1;
    for (int j = 0; j < 16; j++) {
        if (type[j] <= 1) { int k = 0; while (thr[k] != t[j]) k++; pos[j] = k; }
        else pos[j] = 0;
    }
    for (int k = 0; k < 16; k++) bnd[k] = (k < nt) ? thr[k] : 3.4e38f;
    prepI[0] = K;
    for (int k = 0; k < K; k++) {
        unsigned m = 0;
        for (int j = 0; j < 16; j++) {
            bool act;
            if (type[j] == 0)      act = (k >= pos[j] + 1);
            else if (type[j] == 1) act = (k <= pos[j]);
            else                   act = (type[j] == 2);
            if (act) m |= (1u << j);
        }
        prepI[1 + k] = (int)m;
    }
}

__global__ void k_mark(const int* __restrict__ gene_idx, int* __restrict__ slot,
                       int G, int M, int npg, int N) {
    int i = blockIdx.x * blockDim.x + threadIdx.x;
    if (i >= M) return;
    int node = gene_idx[i % G] + (i / G) * npg;
    if ((unsigned)node < (unsigned)N) slot[node] = i;  // race: any winner consistent
}

// ---------- counting sort by dst range ----------

__global__ void k_hist(const int* __restrict__ src, const int* __restrict__ dst,
                       int* __restrict__ histG, int E, int N, int R) {
    __shared__ int h[512];
    for (int i = threadIdx.x; i < R; i += blockDim.x) h[i] = 0;
    __syncthreads();
    for (int e = blockIdx.x * blockDim.x + threadIdx.x; e < E; e += gridDim.x * blockDim.x) {
        int d = dst[e], s = src[e];
        if ((unsigned)d < (unsigned)N && (unsigned)s < (unsigned)N)
            atomicAdd(&h[d >> RS_BITS], 1);
    }
    __syncthreads();
    for (int i = threadIdx.x; i < R; i += blockDim.x) {
        int c = h[i];
        if (c) atomicAdd(&histG[i], c);
    }
}

__global__ void k_scan(const int* __restrict__ histG, int* __restrict__ base,
                       int* __restrict__ cursor, int R) {
    __shared__ int a[512];
    int t = threadIdx.x;
    int v = (t < R) ? histG[t] : 0;
    a[t] = v;
    __syncthreads();
    for (int off = 1; off < 512; off <<= 1) {
        int add = (t >= off) ? a[t - off] : 0;
        __syncthreads();
        a[t] += add;
        __syncthreads();
    }
    if (t < R) { int ex = a[t] - v; base[t] = ex; cursor[t] = ex; }
}

// Tile-wise bucket scatter with LDS chunk reservation: ~R global int atomics/tile.
__global__ void k_bucket(const int* __restrict__ src, const int* __restrict__ dst,
                         int* __restrict__ cursorG, unsigned* __restrict__ bucket,
                         int E, int N, int R) {
    __shared__ int cnt[512];
    __shared__ int baseL[512];
    int tile0 = blockIdx.x * TILE;
    for (int i = threadIdx.x; i < R; i += 256) cnt[i] = 0;
    __syncthreads();
    int ds[EPT], ss[EPT];
#pragma unroll
    for (int i = 0; i < EPT; i++) {
        int e = tile0 + i * 256 + threadIdx.x;
        ds[i] = -1;
        if (e < E) {
            int d = dst[e], s = src[e];
            if ((unsigned)d < (unsigned)N && (unsigned)s < (unsigned)N) {
                ds[i] = d; ss[i] = s;
                atomicAdd(&cnt[d >> RS_BITS], 1);
            }
        }
    }
    __syncthreads();
    for (int r = threadIdx.x; r < R; r += 256) {
        int c = cnt[r];
        baseL[r] = c > 0 ? atomicAdd(&cursorG[r], c) : 0;
        cnt[r] = 0;
    }
    __syncthreads();
#pragma unroll
    for (int i = 0; i < EPT; i++) {
        int d = ds[i];
        if (d < 0) continue;
        int r = d >> RS_BITS;
        int o = atomicAdd(&cnt[r], 1);
        int idx = baseL[r] + o;
        if ((unsigned)idx < (unsigned)E)   // defensive: OOB -> dropped edge, not fault
            bucket[idx] = ((unsigned)(d & (RS - 1)) << SRC_BITS) | (unsigned)ss[i];
    }
}

// Per-range degree via LDS histogram (no global atomics).
__global__ void k_degR(const unsigned* __restrict__ bucket, const int* __restrict__ base,
                       const int* __restrict__ histG, int* __restrict__ degI, int N, int E) {
    __shared__ int degL[RS];
    int r = blockIdx.x;
    int nb = base[r];
    int cnt = min(histG[r], E - nb);
    for (int i = threadIdx.x; i < RS; i += 256) degL[i] = 0;
    __syncthreads();
    for (int i = threadIdx.x; i < cnt; i += 256)
        atomicAdd(&degL[bucket[nb + i] >> SRC_BITS], 1);
    __syncthreads();
    int b0 = r << RS_BITS;
    for (int i = threadIdx.x; i < RS; i += 256) {
        int v = b0 + i;
        if (v < N) degI[v] = degL[i];
    }
}

__global__ void k_dinvI(const int* __restrict__ degI, float* __restrict__ dinv, int N) {
    int v = blockIdx.x * blockDim.x + threadIdx.x;
    if (v < N) dinv[v] = rsqrtf((float)degI[v] + 1.0f);  // +1 self-loop
}

// Per-range t1[v] = sum over in-edges of x[src]*dinv[src] (LDS float atomics).
__global__ void k_t1R(const unsigned* __restrict__ bucket, const int* __restrict__ base,
                      const int* __restrict__ histG, const float* __restrict__ x,
                      const float* __restrict__ dinv, float* __restrict__ t1, int N, int E) {
    __shared__ float accL[RS];
    int r = blockIdx.x;
    int nb = base[r];
    int cnt = min(histG[r], E - nb);
    for (int i = threadIdx.x; i < RS; i += 256) accL[i] = 0.f;
    __syncthreads();
    for (int i = threadIdx.x; i < cnt; i += 256) {
        unsigned e = bucket[nb + i];
        int sv = (int)(e & SRC_MASK);
        atomicAdd(&accL[e >> SRC_BITS], x[sv] * dinv[sv]);
    }
    __syncthreads();
    int b0 = r << RS_BITS;
    for (int i = threadIdx.x; i < RS; i += 256) {
        int v = b0 + i;
        if (v < N) t1[v] = accL[i];
    }
}

// s[v] = dinv[v]*(t1[v] + x[v]*dinv[v]), stored into t1.
__global__ void k_s2(const float* __restrict__ x, const float* __restrict__ dinv,
                     float* __restrict__ t1, int N) {
    int v = blockIdx.x * blockDim.x + threadIdx.x;
    if (v < N) {
        float di = dinv[v];
        t1[v] = di * (t1[v] + x[v] * di);
    }
}

// Per-range layer-2 bucket sums in LDS (K<=4 fast path; exits otherwise).
__global__ void k_aggR(const unsigned* __restrict__ bucket, const int* __restrict__ base,
                       const int* __restrict__ histG, const float* __restrict__ s,
                       const float* __restrict__ dinv, const int* __restrict__ slot,
                       const float* __restrict__ bnd, const int* __restrict__ prepI,
                       float* __restrict__ aggb, int N, int E) {
    __shared__ float acc[RS * 8];
    __shared__ int slotL[RS];
    __shared__ float sB[3];
    __shared__ int sK;
    if (threadIdx.x == 0) sK = prepI[0];
    if (threadIdx.x < 3) sB[threadIdx.x] = bnd[threadIdx.x];
    __syncthreads();
    int K = sK;
    if (K > 4) return;
    int r = blockIdx.x;
    int b0 = r << RS_BITS;
    for (int i = threadIdx.x; i < RS; i += 256) {
        int v = b0 + i;
        slotL[i] = (v < N) ? slot[v] : -1;
    }
    for (int i = threadIdx.x; i < RS * 8; i += 256) acc[i] = 0.f;
    __syncthreads();
    int nb = base[r];
    int cnt = min(histG[r], E - nb);
    for (int i = threadIdx.x; i < cnt; i += 256) {
        unsigned e = bucket[nb + i];
        int l = (int)(e >> SRC_BITS);
        if (slotL[l] < 0) continue;
        int sv = (int)(e & SRC_MASK);
        float sval = s[sv], di = dinv[sv];
        int b = 0;
        for (int k = 0; k < K - 1; k++) b += (sval > sB[k]) ? 1 : 0;
        atomicAdd(&acc[l * 8 + 2 * b], sval * di);
        atomicAdd(&acc[l * 8 + 2 * b + 1], di);
    }
    __syncthreads();
    for (int i = threadIdx.x; i < RS; i += 256) {
        int sl = slotL[i];
        if (sl < 0) continue;
        float* row = aggb + (size_t)sl * (2 * MAXB);
        for (int k = 0; k < K; k++) {
            row[2 * k]     = acc[i * 8 + 2 * k];
            row[2 * k + 1] = acc[i * 8 + 2 * k + 1];
        }
    }
}

// ---------- fallback path (R4 kernels, global atomics) ----------

__global__ void k_deg(const int* __restrict__ dst, float* __restrict__ deg, int E, int N) {
    int e = blockIdx.x * blockDim.x + threadIdx.x;
    if (e >= E) return;
    int d = dst[e];
    if ((unsigned)d < (unsigned)N) atomicAdd(&deg[d], 1.0f);
}

__global__ void k_dinv_p(const float* __restrict__ x, float* __restrict__ degv,
                         float* __restrict__ p, int N) {
    int v = blockIdx.x * blockDim.x + threadIdx.x;
    if (v < N) {
        float di = rsqrtf(degv[v] + 1.0f);
        degv[v] = di;
        p[v] = x[v] * di;
    }
}

__global__ void k_scatter1(const int* __restrict__ src, const int* __restrict__ dst,
                           const float* __restrict__ p, float* __restrict__ t1, int E, int N) {
    int e = blockIdx.x * blockDim.x + threadIdx.x;
    if (e >= E) return;
    int s = src[e];
    int d = dst[e];
    if ((unsigned)s < (unsigned)N && (unsigned)d < (unsigned)N)
        atomicAdd(&t1[d], p[s]);
}

__global__ void k_s(const float* __restrict__ p, const float* __restrict__ dinv,
                    float* __restrict__ t1, int N) {
    int v = blockIdx.x * blockDim.x + threadIdx.x;
    if (v < N) t1[v] = dinv[v] * (t1[v] + p[v]);
}

// General bucket scatter with global atomics. force=1: always run (fallback path).
// force=0: only runs when K>4 (new path's rare fallback).
__global__ void k_agg_atomic(const int* __restrict__ src, const int* __restrict__ dst,
                             const float* __restrict__ s, const float* __restrict__ dinv,
                             const int* __restrict__ slot,
                             const float* __restrict__ bnd, const int* __restrict__ prepI,
                             float* __restrict__ aggb, int E, int N, int force) {
    __shared__ float sB[16];
    __shared__ int sK;
    if (threadIdx.x == 0) sK = prepI[0];
    if (threadIdx.x < 16) sB[threadIdx.x] = bnd[threadIdx.x];
    __syncthreads();
    int K = sK;
    if (!force && K <= 4) return;
    int T = K - 1;
    for (int e = blockIdx.x * blockDim.x + threadIdx.x; e < E; e += gridDim.x * blockDim.x) {
        int d = dst[e];
        if ((unsigned)d >= (unsigned)N) continue;
        int sl = slot[d];
        if (sl < 0) continue;
        int sv = src[e];
        if ((unsigned)sv >= (unsigned)N) continue;
        float sval = s[sv];
        float di = dinv[sv];
        int b = 0;
        for (int i = 0; i < T; i++) b += (sval > sB[i]) ? 1 : 0;
        float* row = aggb + (size_t)sl * (2 * MAXB) + 2 * b;
        atomicAdd(row, sval * di);
        atomicAdd(row + 1, di);
    }
}

// Head: reconstruct agg features from buckets, add self term, W2+relu, fc1+relu, fc2.
__global__ void k_final(const float* __restrict__ aggb, const float* __restrict__ s,
                        const float* __restrict__ dinv,
                        const int* __restrict__ gene_idx, const int* __restrict__ slot,
                        const int* __restrict__ prepI,
                        const float* __restrict__ W1, const float* __restrict__ b1,
                        const float* __restrict__ W2, const float* __restrict__ b2,
                        const float* __restrict__ f1W, const float* __restrict__ f1b,
                        const float* __restrict__ f2W, const float* __restrict__ f2b,
                        float* __restrict__ out, int G, int M, int npg, int N) {
    __shared__ float sW1[16], sb1[16], sW2[256], sb2[16], sf1[128], sf1b[8], sf2[8], sf2b[1];
    __shared__ int sMask[MAXB], sK;
    for (int i = threadIdx.x; i < 256; i += blockDim.x) sW2[i] = W2[i];
    for (int i = threadIdx.x; i < 128; i += blockDim.x) sf1[i] = f1W[i];
    if (threadIdx.x < 16) { sW1[threadIdx.x] = W1[threadIdx.x]; sb1[threadIdx.x] = b1[threadIdx.x]; sb2[threadIdx.x] = b2[threadIdx.x]; }
    if (threadIdx.x < 8)  { sf1b[threadIdx.x] = f1b[threadIdx.x]; sf2[threadIdx.x] = f2W[threadIdx.x]; }
    if (threadIdx.x == 0) { sf2b[0] = f2b[0]; sK = prepI[0]; }
    if (threadIdx.x < MAXB) sMask[threadIdx.x] = prepI[1 + threadIdx.x];
    __syncthreads();

    int i = blockIdx.x * blockDim.x + threadIdx.x;
    if (i >= M) return;
    int node = gene_idx[i % G] + (i / G) * npg;
    if ((unsigned)node >= (unsigned)N) { out[i] = 0.0f; return; }
    int sl = slot[node];

    float di = dinv[node];
    float sval = s[node];
    int K = sK;

    float bu[MAXB], bw[MAXB];
    if (sl >= 0) {
        const float* row = aggb + (size_t)sl * (2 * MAXB);
        for (int k = 0; k < K; k++) { bu[k] = row[2 * k]; bw[k] = row[2 * k + 1]; }
    } else {
        for (int k = 0; k < K; k++) { bu[k] = 0.f; bw[k] = 0.f; }
    }

    float a[16];
#pragma unroll
    for (int j = 0; j < 16; j++) {
        float Su = 0.f, Sw = 0.f;
        for (int k = 0; k < K; k++) {
            if ((sMask[k] >> j) & 1) { Su += bu[k]; Sw += bw[k]; }
        }
        float aggj = sW1[j] * Su + sb1[j] * Sw;
        float qself = fmaxf(fmaf(sW1[j], sval, sb1[j]), 0.0f) * di;
        a[j] = di * (aggj + qself);
    }
    float h2[16];
#pragma unroll
    for (int j = 0; j < 16; j++) {
        float acc = sb2[j];
#pragma unroll
        for (int k = 0; k < 16; k++) acc = fmaf(a[k], sW2[k * 16 + j], acc);
        h2[j] = fmaxf(acc, 0.0f);
    }
    float f1[8];
#pragma unroll
    for (int j = 0; j < 8; j++) {
        float acc = sf1b[j];
#pragma unroll
        for (int k = 0; k < 16; k++) acc = fmaf(h2[k], sf1[k * 8 + j], acc);
        f1[j] = fmaxf(acc, 0.0f);
    }
    float o = sf2b[0];
#pragma unroll
    for (int k = 0; k < 8; k++) o = fmaf(f1[k], sf2[k], o);
    out[i] = o;
}

extern "C" void kernel_launch(void* const* d_in, const int* in_sizes, int n_in,
                              void* d_out, int out_size, void* d_ws, size_t ws_size,
                              hipStream_t stream) {
    const float* x        = (const float*)d_in[0];
    const int*   ei       = (const int*)d_in[1];
    const int*   gene_idx = (const int*)d_in[3];
    const float* W1  = (const float*)d_in[5];
    const float* b1  = (const float*)d_in[6];
    const float* W2  = (const float*)d_in[7];
    const float* b2  = (const float*)d_in[8];
    const float* f1W = (const float*)d_in[9];
    const float* f1b = (const float*)d_in[10];
    const float* f2W = (const float*)d_in[11];
    const float* f2b = (const float*)d_in[12];
    float* out = (float*)d_out;

    int N = in_sizes[0];       // 320000
    int E = in_sizes[1] / 2;   // 5120000
    int M = in_sizes[2];       // 32000 (= reps * G)
    int G = in_sizes[3];       // 1000
    int npg = (int)(((long long)N * (long long)G) / (long long)M);  // N / num_graphs

    const int* src = ei;
    const int* dst = ei + E;

    int R = (N + RS - 1) >> RS_BITS;  // #ranges (<=512 when N < 2^19)
    const int tb = 256;

    // New-path layout (4B units):
    float* ws = (float*)d_ws;
    size_t off = 0;
    float*    dinvF  = ws + off;            off += (size_t)N;
    float*    t1     = ws + off;            off += (size_t)N;
    int*      slot   = (int*)(ws + off);    off += (size_t)N;
    float*    aggb   = ws + off;            // degI overlays aggb (degI dead before fill)
    int*      degI   = (int*)aggb;          off += (size_t)2 * MAXB * M;
    unsigned* bucket = (unsigned*)(ws + off); off += (size_t)E;
    int*      histG  = (int*)(ws + off);    off += (size_t)R;
    int*      baseA  = (int*)(ws + off);    off += (size_t)R;
    int*      cursor = (int*)(ws + off);    off += (size_t)R;
    float*    bnd    = ws + off;            off += 16;
    int*      prepI  = (int*)(ws + off);    off += 20;
    size_t need = off * 4;

    bool use_new = (ws_size >= need) && (N < (1 << SRC_BITS)) &&
                   ((size_t)2 * MAXB * M >= (size_t)N) && (R <= 512);

    if (use_new) {
        k_fill_i<<<(N + tb - 1) / tb, tb, 0, stream>>>(slot, -1, N);
        k_fill_i<<<(R + tb - 1) / tb, tb, 0, stream>>>(histG, 0, R);   // <-- R5 bugfix
        k_prep<<<1, 64, 0, stream>>>(W1, b1, bnd, prepI);
        k_mark<<<(M + tb - 1) / tb, tb, 0, stream>>>(gene_idx, slot, G, M, npg, N);
        k_hist<<<512, tb, 0, stream>>>(src, dst, histG, E, N, R);
        k_scan<<<1, 512, 0, stream>>>(histG, baseA, cursor, R);
        int ntiles = (E + TILE - 1) / TILE;
        k_bucket<<<ntiles, tb, 0, stream>>>(src, dst, cursor, bucket, E, N, R);
        k_degR<<<R, tb, 0, stream>>>(bucket, baseA, histG, degI, N, E);
        k_dinvI<<<(N + tb - 1) / tb, tb, 0, stream>>>(degI, dinvF, N);
        k_fill_f<<<(2 * MAXB * M + tb - 1) / tb, tb, 0, stream>>>(aggb, 0.0f, 2 * MAXB * M);
        k_t1R<<<R, tb, 0, stream>>>(bucket, baseA, histG, x, dinvF, t1, N, E);
        k_s2<<<(N + tb - 1) / tb, tb, 0, stream>>>(x, dinvF, t1, N);
        k_aggR<<<R, tb, 0, stream>>>(bucket, baseA, histG, t1, dinvF, slot, bnd, prepI,
                                     aggb, N, E);
        k_agg_atomic<<<2048, tb, 0, stream>>>(src, dst, t1, dinvF, slot, bnd, prepI,
                                              aggb, E, N, /*force=*/0);
        k_final<<<(M + tb - 1) / tb, tb, 0, stream>>>(aggb, t1, dinvF, gene_idx, slot, prepI,
                                                      W1, b1, W2, b2, f1W, f1b, f2W, f2b,
                                                      out, G, M, npg, N);
    } else {
        // Fallback: R4 layout/path
        float* deg   = ws;                          // N (becomes dinv)
        float* t1o   = ws + (size_t)N;              // N (becomes s)
        float* p     = ws + 2 * (size_t)N;          // N
        int*   slotO = (int*)(ws + 3 * (size_t)N);  // N
        float* aggbO = ws + 4 * (size_t)N;          // 2*MAXB*M
        float* bndO  = aggbO + (size_t)2 * MAXB * M;
        int*   prepO = (int*)(bndO + 16);

        k_fill_f<<<(2 * N + tb - 1) / tb, tb, 0, stream>>>(deg, 0.0f, 2 * N);
        k_fill_i<<<(N + tb - 1) / tb, tb, 0, stream>>>(slotO, -1, N);
        k_fill_f<<<(2 * MAXB * M + tb - 1) / tb, tb, 0, stream>>>(aggbO, 0.0f, 2 * MAXB * M);
        k_prep<<<1, 64, 0, stream>>>(W1, b1, bndO, prepO);
        k_mark<<<(M + tb - 1) / tb, tb, 0, stream>>>(gene_idx, slotO, G, M, npg, N);
        k_deg<<<(E + tb - 1) / tb, tb, 0, stream>>>(dst, deg, E, N);
        k_dinv_p<<<(N + tb - 1) / tb, tb, 0, stream>>>(x, deg, p, N);
        k_scatter1<<<(E + tb - 1) / tb, tb, 0, stream>>>(src, dst, p, t1o, E, N);
        k_s<<<(N + tb - 1) / tb, tb, 0, stream>>>(p, deg, t1o, N);
        k_agg_atomic<<<2048, tb, 0, stream>>>(src, dst, t1o, deg, slotO, bndO, prepO,
                                              aggbO, E, N, /*force=*/1);
        k_final<<<(M + tb - 1) / tb, tb, 0, stream>>>(aggbO, t1o, deg, gene_idx, slotO, prepO,
                                                      W1, b1, W2, b2, f1W, f1b, f2W, f2b,
                                                      out, G, M, npg, N);
    }
}

// Round 7
// 270.815 us; speedup vs baseline: 3.8855x; 1.3092x over previous
//
#include <hip/hip_runtime.h>

// Fused multi-graph GCN inference (N=320k, E=5.12M, features 1->16->16->8->1).
// Layer-1 collapses to a scalar per node; layer-2 uses the relu-threshold bucket
// trick. Edges counting-sorted by dst-range (1024 nodes/range); per-edge
// aggregation in LDS. R7: per-range kernels at 1024 thr (16 waves) + uint4
// bucket reads (ILP) + packed (s,dinv) float2 + p[] precompute — attacks the
// 9% occupancy latency-bound profile of R6's k_t1R/k_aggR/k_degR.

#define MAXB 17          // max relu buckets (16 thresholds + 1)
#define RS_BITS 10
#define RS (1 << RS_BITS)        // nodes per range
#define SRC_BITS 19              // N must be < 2^19
#define SRC_MASK ((1u << SRC_BITS) - 1u)
#define BT 1024                  // block threads for per-range kernels
#define EPT 16                   // edges per thread in k_bucket
#define TILE (BT * EPT)

__global__ void k_fill_f(float* __restrict__ w, float v, int n) {
    int i = blockIdx.x * blockDim.x + threadIdx.x;
    if (i < n) w[i] = v;
}
__global__ void k_fill_i(int* __restrict__ w, int v, int n) {
    int i = blockIdx.x * blockDim.x + threadIdx.x;
    if (i < n) w[i] = v;
}

// Single-thread prep: sorted unique relu thresholds + per-bucket active masks.
__global__ void k_prep(const float* __restrict__ W1, const float* __restrict__ b1,
                       float* __restrict__ bnd, int* __restrict__ prepI) {
    if (threadIdx.x != 0 || blockIdx.x != 0) return;
    float t[16]; int type[16]; int pos[16];
    float thr[16]; int nt = 0;
    for (int j = 0; j < 16; j++) {
        float W = W1[j], B = b1[j];
        if (W > 0.f)      { type[j] = 0; t[j] = -B / W; }   // active iff s > t
        else if (W < 0.f) { type[j] = 1; t[j] = -B / W; }   // active iff s < t
        else              { type[j] = (B > 0.f) ? 2 : 3; t[j] = 0.f; }
    }
    for (int j = 0; j < 16; j++) {
        if (type[j] > 1) continue;
        float v = t[j];
        int k = 0; while (k < nt && thr[k] < v) k++;
        if (!(k < nt && thr[k] == v)) {
            for (int m = nt; m > k; m--) thr[m] = thr[m - 1];
            thr[k] = v; nt++;
        }
    }
    int K = nt + 1;
    for (int j = 0; j < 16; j++) {
        if (type[j] <= 1) { int k = 0; while (thr[k] != t[j]) k++; pos[j] = k; }
        else pos[j] = 0;
    }
    for (int k = 0; k < 16; k++) bnd[k] = (k < nt) ? thr[k] : 3.4e38f;
    prepI[0] = K;
    for (int k = 0; k < K; k++) {
        unsigned m = 0;
        for (int j = 0; j < 16; j++) {
            bool act;
            if (type[j] == 0)      act = (k >= pos[j] + 1);
            else if (type[j] == 1) act = (k <= pos[j]);
            else                   act = (type[j] == 2);
            if (act) m |= (1u << j);
        }
        prepI[1 + k] = (int)m;
    }
}

__global__ void k_mark(const int* __restrict__ gene_idx, int* __restrict__ slot,
                       int G, int M, int npg, int N) {
    int i = blockIdx.x * blockDim.x + threadIdx.x;
    if (i >= M) return;
    int node = gene_idx[i % G] + (i / G) * npg;
    if ((unsigned)node < (unsigned)N) slot[node] = i;  // race: any winner consistent
}

// ---------- counting sort by dst range ----------

__global__ void k_hist(const int* __restrict__ dst, int* __restrict__ histG,
                       int E, int N, int R) {
    __shared__ int h[512];
    for (int i = threadIdx.x; i < R; i += blockDim.x) h[i] = 0;
    __syncthreads();
    for (int e = blockIdx.x * blockDim.x + threadIdx.x; e < E; e += gridDim.x * blockDim.x) {
        int d = dst[e];
        if ((unsigned)d < (unsigned)N) atomicAdd(&h[d >> RS_BITS], 1);
    }
    __syncthreads();
    for (int i = threadIdx.x; i < R; i += blockDim.x) {
        int c = h[i];
        if (c) atomicAdd(&histG[i], c);
    }
}

// Exclusive scan of counts PADDED to %4 so every range base is 16B-aligned.
__global__ void k_scan(const int* __restrict__ histG, int* __restrict__ base,
                       int* __restrict__ cursor, int R) {
    __shared__ int a[512];
    int t = threadIdx.x;
    int v = (t < R) ? ((histG[t] + 3) & ~3) : 0;
    a[t] = v;
    __syncthreads();
    for (int off = 1; off < 512; off <<= 1) {
        int add = (t >= off) ? a[t - off] : 0;
        __syncthreads();
        a[t] += add;
        __syncthreads();
    }
    if (t < R) { int ex = a[t] - v; base[t] = ex; cursor[t] = ex; }
}

// Tile-wise bucket scatter with LDS chunk reservation.
__global__ void k_bucket(const int* __restrict__ src, const int* __restrict__ dst,
                         int* __restrict__ cursorG, unsigned* __restrict__ bucket,
                         int E, int N, int R, int cap) {
    __shared__ int cnt[512];
    __shared__ int baseL[512];
    int tile0 = blockIdx.x * TILE;
    for (int i = threadIdx.x; i < R; i += BT) cnt[i] = 0;
    __syncthreads();
    int ds[EPT], ss[EPT];
#pragma unroll
    for (int i = 0; i < EPT; i++) {
        int e = tile0 + i * BT + threadIdx.x;
        ds[i] = -1;
        if (e < E) {
            int d = dst[e], s = src[e];
            if ((unsigned)d < (unsigned)N && (unsigned)s < (unsigned)N) {
                ds[i] = d; ss[i] = s;
                atomicAdd(&cnt[d >> RS_BITS], 1);
            }
        }
    }
    __syncthreads();
    for (int r = threadIdx.x; r < R; r += BT) {
        int c = cnt[r];
        baseL[r] = c > 0 ? atomicAdd(&cursorG[r], c) : 0;
        cnt[r] = 0;
    }
    __syncthreads();
#pragma unroll
    for (int i = 0; i < EPT; i++) {
        int d = ds[i];
        if (d < 0) continue;
        int r = d >> RS_BITS;
        int o = atomicAdd(&cnt[r], 1);
        int idx = baseL[r] + o;
        if ((unsigned)idx < (unsigned)cap)   // defensive: drop, don't fault
            bucket[idx] = ((unsigned)(d & (RS - 1)) << SRC_BITS) | (unsigned)ss[i];
    }
}

// Per-range degree via LDS histogram. 1024 thr, uint4 reads.
__global__ void __launch_bounds__(BT)
k_degR(const unsigned* __restrict__ bucket, const int* __restrict__ base,
       const int* __restrict__ histG, int* __restrict__ degI, int N, int cap) {
    __shared__ int degL[RS];
    int r = blockIdx.x;
    int nb = base[r];
    int cnt = min(histG[r], cap - nb);
    for (int i = threadIdx.x; i < RS; i += BT) degL[i] = 0;
    __syncthreads();
    for (int i = threadIdx.x * 4; i < cnt; i += BT * 4) {
        uint4 e4 = *(const uint4*)(bucket + nb + i);  // padded region: safe
        if (i + 0 < cnt) atomicAdd(&degL[e4.x >> SRC_BITS], 1);
        if (i + 1 < cnt) atomicAdd(&degL[e4.y >> SRC_BITS], 1);
        if (i + 2 < cnt) atomicAdd(&degL[e4.z >> SRC_BITS], 1);
        if (i + 3 < cnt) atomicAdd(&degL[e4.w >> SRC_BITS], 1);
    }
    __syncthreads();
    int b0 = r << RS_BITS;
    for (int i = threadIdx.x; i < RS; i += BT) {
        int v = b0 + i;
        if (v < N) degI[v] = degL[i];
    }
}

// dinv + p from integer degree: sd[2v+1] = dinv, p[v] = x[v]*dinv.
__global__ void k_dinvp(const int* __restrict__ degI, const float* __restrict__ x,
                        float* __restrict__ sd, float* __restrict__ p, int N) {
    int v = blockIdx.x * blockDim.x + threadIdx.x;
    if (v < N) {
        float di = rsqrtf((float)degI[v] + 1.0f);  // +1 self-loop
        sd[2 * v + 1] = di;
        p[v] = x[v] * di;
    }
}

// Per-range t1[v] = sum p[src] over in-edges -> sd[2v]. 1024 thr, uint4 reads.
__global__ void __launch_bounds__(BT)
k_t1R(const unsigned* __restrict__ bucket, const int* __restrict__ base,
      const int* __restrict__ histG, const float* __restrict__ p,
      float* __restrict__ sd, int N, int cap) {
    __shared__ float accL[RS];
    int r = blockIdx.x;
    int nb = base[r];
    int cnt = min(histG[r], cap - nb);
    for (int i = threadIdx.x; i < RS; i += BT) accL[i] = 0.f;
    __syncthreads();
    for (int i = threadIdx.x * 4; i < cnt; i += BT * 4) {
        uint4 e4 = *(const uint4*)(bucket + nb + i);
        if (i + 0 < cnt) atomicAdd(&accL[e4.x >> SRC_BITS], p[e4.x & SRC_MASK]);
        if (i + 1 < cnt) atomicAdd(&accL[e4.y >> SRC_BITS], p[e4.y & SRC_MASK]);
        if (i + 2 < cnt) atomicAdd(&accL[e4.z >> SRC_BITS], p[e4.z & SRC_MASK]);
        if (i + 3 < cnt) atomicAdd(&accL[e4.w >> SRC_BITS], p[e4.w & SRC_MASK]);
    }
    __syncthreads();
    int b0 = r << RS_BITS;
    for (int i = threadIdx.x; i < RS; i += BT) {
        int v = b0 + i;
        if (v < N) sd[2 * v] = accL[i];
    }
}

// sd[2v] <- s[v] = dinv*(t1 + p)   (p = x*dinv)
__global__ void k_s2(const float* __restrict__ p, float* __restrict__ sd, int N) {
    int v = blockIdx.x * blockDim.x + threadIdx.x;
    if (v < N) {
        float di = sd[2 * v + 1];
        sd[2 * v] = di * (sd[2 * v] + p[v]);
    }
}

// Per-range layer-2 bucket sums in LDS (K<=4 fast path). 1024 thr, uint4 + float2.
__global__ void __launch_bounds__(BT)
k_aggR(const unsigned* __restrict__ bucket, const int* __restrict__ base,
       const int* __restrict__ histG, const float* __restrict__ sd,
       const int* __restrict__ slot, const float* __restrict__ bnd,
       const int* __restrict__ prepI, float* __restrict__ aggb, int N, int cap) {
    __shared__ float acc[RS * 8];
    __shared__ int slotL[RS];
    __shared__ float sB[3];
    __shared__ int sK;
    if (threadIdx.x == 0) sK = prepI[0];
    if (threadIdx.x < 3) sB[threadIdx.x] = bnd[threadIdx.x];
    __syncthreads();
    int K = sK;
    if (K > 4) return;
    int r = blockIdx.x;
    int b0 = r << RS_BITS;
    for (int i = threadIdx.x; i < RS; i += BT) {
        int v = b0 + i;
        slotL[i] = (v < N) ? slot[v] : -1;
    }
    for (int i = threadIdx.x; i < RS * 8; i += BT) acc[i] = 0.f;
    __syncthreads();
    int nb = base[r];
    int cnt = min(histG[r], cap - nb);
    const float2* sd2 = (const float2*)sd;
    for (int i = threadIdx.x * 4; i < cnt; i += BT * 4) {
        uint4 e4 = *(const uint4*)(bucket + nb + i);
        unsigned ee[4] = {e4.x, e4.y, e4.z, e4.w};
#pragma unroll
        for (int k4 = 0; k4 < 4; k4++) {
            if (i + k4 >= cnt) break;
            unsigned e = ee[k4];
            int l = (int)(e >> SRC_BITS);
            if (slotL[l] < 0) continue;
            float2 v = sd2[e & SRC_MASK];
            int b = 0;
            for (int k = 0; k < K - 1; k++) b += (v.x > sB[k]) ? 1 : 0;
            atomicAdd(&acc[l * 8 + 2 * b], v.x * v.y);
            atomicAdd(&acc[l * 8 + 2 * b + 1], v.y);
        }
    }
    __syncthreads();
    for (int i = threadIdx.x; i < RS; i += BT) {
        int sl = slotL[i];
        if (sl < 0) continue;
        float* row = aggb + (size_t)sl * (2 * MAXB);
        for (int k = 0; k < K; k++) {
            row[2 * k]     = acc[i * 8 + 2 * k];
            row[2 * k + 1] = acc[i * 8 + 2 * k + 1];
        }
    }
}

// ---------- generic / fallback kernels (strided s,dinv access) ----------

__global__ void k_deg(const int* __restrict__ dst, float* __restrict__ deg, int E, int N) {
    int e = blockIdx.x * blockDim.x + threadIdx.x;
    if (e >= E) return;
    int d = dst[e];
    if ((unsigned)d < (unsigned)N) atomicAdd(&deg[d], 1.0f);
}

__global__ void k_dinv_p(const float* __restrict__ x, float* __restrict__ degv,
                         float* __restrict__ p, int N) {
    int v = blockIdx.x * blockDim.x + threadIdx.x;
    if (v < N) {
        float di = rsqrtf(degv[v] + 1.0f);
        degv[v] = di;
        p[v] = x[v] * di;
    }
}

__global__ void k_scatter1(const int* __restrict__ src, const int* __restrict__ dst,
                           const float* __restrict__ p, float* __restrict__ t1, int E, int N) {
    int e = blockIdx.x * blockDim.x + threadIdx.x;
    if (e >= E) return;
    int s = src[e];
    int d = dst[e];
    if ((unsigned)s < (unsigned)N && (unsigned)d < (unsigned)N)
        atomicAdd(&t1[d], p[s]);
}

__global__ void k_s(const float* __restrict__ p, const float* __restrict__ dinv,
                    float* __restrict__ t1, int N) {
    int v = blockIdx.x * blockDim.x + threadIdx.x;
    if (v < N) t1[v] = dinv[v] * (t1[v] + p[v]);
}

// Bucket scatter with global atomics; s/dinv accessed with stride `str`.
// force=1: always run (fallback). force=0: only when K>4 (new path's rare case).
__global__ void k_agg_atomic(const int* __restrict__ src, const int* __restrict__ dst,
                             const float* __restrict__ sA, const float* __restrict__ dA,
                             int str, const int* __restrict__ slot,
                             const float* __restrict__ bnd, const int* __restrict__ prepI,
                             float* __restrict__ aggb, int E, int N, int force) {
    __shared__ float sB[16];
    __shared__ int sK;
    if (threadIdx.x == 0) sK = prepI[0];
    if (threadIdx.x < 16) sB[threadIdx.x] = bnd[threadIdx.x];
    __syncthreads();
    int K = sK;
    if (!force && K <= 4) return;
    int T = K - 1;
    for (int e = blockIdx.x * blockDim.x + threadIdx.x; e < E; e += gridDim.x * blockDim.x) {
        int d = dst[e];
        if ((unsigned)d >= (unsigned)N) continue;
        int sl = slot[d];
        if (sl < 0) continue;
        int sv = src[e];
        if ((unsigned)sv >= (unsigned)N) continue;
        float sval = sA[(size_t)sv * str];
        float di = dA[(size_t)sv * str];
        int b = 0;
        for (int i = 0; i < T; i++) b += (sval > sB[i]) ? 1 : 0;
        float* row = aggb + (size_t)sl * (2 * MAXB) + 2 * b;
        atomicAdd(row, sval * di);
        atomicAdd(row + 1, di);
    }
}

// Head: reconstruct agg from buckets, add self term, W2+relu, fc1+relu, fc2.
__global__ void k_final(const float* __restrict__ aggb, const float* __restrict__ sA,
                        const float* __restrict__ dA, int str,
                        const int* __restrict__ gene_idx, const int* __restrict__ slot,
                        const int* __restrict__ prepI,
                        const float* __restrict__ W1, const float* __restrict__ b1,
                        const float* __restrict__ W2, const float* __restrict__ b2,
                        const float* __restrict__ f1W, const float* __restrict__ f1b,
                        const float* __restrict__ f2W, const float* __restrict__ f2b,
                        float* __restrict__ out, int G, int M, int npg, int N) {
    __shared__ float sW1[16], sb1[16], sW2[256], sb2[16], sf1[128], sf1b[8], sf2[8], sf2b[1];
    __shared__ int sMask[MAXB], sK;
    for (int i = threadIdx.x; i < 256; i += blockDim.x) sW2[i] = W2[i];
    for (int i = threadIdx.x; i < 128; i += blockDim.x) sf1[i] = f1W[i];
    if (threadIdx.x < 16) { sW1[threadIdx.x] = W1[threadIdx.x]; sb1[threadIdx.x] = b1[threadIdx.x]; sb2[threadIdx.x] = b2[threadIdx.x]; }
    if (threadIdx.x < 8)  { sf1b[threadIdx.x] = f1b[threadIdx.x]; sf2[threadIdx.x] = f2W[threadIdx.x]; }
    if (threadIdx.x == 0) { sf2b[0] = f2b[0]; sK = prepI[0]; }
    if (threadIdx.x < MAXB) sMask[threadIdx.x] = prepI[1 + threadIdx.x];
    __syncthreads();

    int i = blockIdx.x * blockDim.x + threadIdx.x;
    if (i >= M) return;
    int node = gene_idx[i % G] + (i / G) * npg;
    if ((unsigned)node >= (unsigned)N) { out[i] = 0.0f; return; }
    int sl = slot[node];

    float di = dA[(size_t)node * str];
    float sval = sA[(size_t)node * str];
    int K = sK;

    float bu[MAXB], bw[MAXB];
    if (sl >= 0) {
        const float* row = aggb + (size_t)sl * (2 * MAXB);
        for (int k = 0; k < K; k++) { bu[k] = row[2 * k]; bw[k] = row[2 * k + 1]; }
    } else {
        for (int k = 0; k < K; k++) { bu[k] = 0.f; bw[k] = 0.f; }
    }

    float a[16];
#pragma unroll
    for (int j = 0; j < 16; j++) {
        float Su = 0.f, Sw = 0.f;
        for (int k = 0; k < K; k++) {
            if ((sMask[k] >> j) & 1) { Su += bu[k]; Sw += bw[k]; }
        }
        float aggj = sW1[j] * Su + sb1[j] * Sw;
        float qself = fmaxf(fmaf(sW1[j], sval, sb1[j]), 0.0f) * di;
        a[j] = di * (aggj + qself);
    }
    float h2[16];
#pragma unroll
    for (int j = 0; j < 16; j++) {
        float acc = sb2[j];
#pragma unroll
        for (int k = 0; k < 16; k++) acc = fmaf(a[k], sW2[k * 16 + j], acc);
        h2[j] = fmaxf(acc, 0.0f);
    }
    float f1[8];
#pragma unroll
    for (int j = 0; j < 8; j++) {
        float acc = sf1b[j];
#pragma unroll
        for (int k = 0; k < 16; k++) acc = fmaf(h2[k], sf1[k * 8 + j], acc);
        f1[j] = fmaxf(acc, 0.0f);
    }
    float o = sf2b[0];
#pragma unroll
    for (int k = 0; k < 8; k++) o = fmaf(f1[k], sf2[k], o);
    out[i] = o;
}

extern "C" void kernel_launch(void* const* d_in, const int* in_sizes, int n_in,
                              void* d_out, int out_size, void* d_ws, size_t ws_size,
                              hipStream_t stream) {
    const float* x        = (const float*)d_in[0];
    const int*   ei       = (const int*)d_in[1];
    const int*   gene_idx = (const int*)d_in[3];
    const float* W1  = (const float*)d_in[5];
    const float* b1  = (const float*)d_in[6];
    const float* W2  = (const float*)d_in[7];
    const float* b2  = (const float*)d_in[8];
    const float* f1W = (const float*)d_in[9];
    const float* f1b = (const float*)d_in[10];
    const float* f2W = (const float*)d_in[11];
    const float* f2b = (const float*)d_in[12];
    float* out = (float*)d_out;

    int N = in_sizes[0];       // 320000
    int E = in_sizes[1] / 2;   // 5120000
    int M = in_sizes[2];       // 32000 (= reps * G)
    int G = in_sizes[3];       // 1000
    int npg = (int)(((long long)N * (long long)G) / (long long)M);  // N / num_graphs

    const int* src = ei;
    const int* dst = ei + E;

    int R = (N + RS - 1) >> RS_BITS;
    int cap = E + 4 * R + 4;          // bucket capacity incl. per-range %4 padding
    const int tb = 256;

    // New-path layout (4B units):
    float* ws = (float*)d_ws;
    size_t off = 0;
    float*    sd     = ws + off;              off += (size_t)2 * N;  // (s,dinv) interleaved
    int*      slot   = (int*)(ws + off);      off += (size_t)N;
    float*    aggb   = ws + off;              // degI overlays aggb[0:N], p overlays aggb[N:2N]
    int*      degI   = (int*)aggb;
    float*    p      = aggb + (size_t)N;      off += (size_t)2 * MAXB * M;
    unsigned* bucket = (unsigned*)(ws + off); off += (size_t)cap;
    int*      histG  = (int*)(ws + off);      off += (size_t)R;
    int*      baseA  = (int*)(ws + off);      off += (size_t)R;
    int*      cursor = (int*)(ws + off);      off += (size_t)R;
    float*    bnd    = ws + off;              off += 16;
    int*      prepI  = (int*)(ws + off);      off += 20;
    size_t need = off * 4;

    bool use_new = (ws_size >= need) && (N < (1 << SRC_BITS)) &&
                   ((size_t)2 * MAXB * M >= (size_t)2 * N) && (R <= 512);

    if (use_new) {
        k_fill_i<<<(N + tb - 1) / tb, tb, 0, stream>>>(slot, -1, N);
        k_fill_i<<<(R + tb - 1) / tb, tb, 0, stream>>>(histG, 0, R);
        k_prep<<<1, 64, 0, stream>>>(W1, b1, bnd, prepI);
        k_mark<<<(M + tb - 1) / tb, tb, 0, stream>>>(gene_idx, slot, G, M, npg, N);
        k_hist<<<512, tb, 0, stream>>>(dst, histG, E, N, R);
        k_scan<<<1, 512, 0, stream>>>(histG, baseA, cursor, R);
        int ntiles = (E + TILE - 1) / TILE;
        k_bucket<<<ntiles, BT, 0, stream>>>(src, dst, cursor, bucket, E, N, R, cap);
        k_degR<<<R, BT, 0, stream>>>(bucket, baseA, histG, degI, N, cap);
        k_dinvp<<<(N + tb - 1) / tb, tb, 0, stream>>>(degI, x, sd, p, N);
        k_t1R<<<R, BT, 0, stream>>>(bucket, baseA, histG, p, sd, N, cap);
        k_s2<<<(N + tb - 1) / tb, tb, 0, stream>>>(p, sd, N);
        k_fill_f<<<(2 * MAXB * M + tb - 1) / tb, tb, 0, stream>>>(aggb, 0.0f, 2 * MAXB * M);
        k_aggR<<<R, BT, 0, stream>>>(bucket, baseA, histG, sd, slot, bnd, prepI, aggb, N, cap);
        k_agg_atomic<<<2048, tb, 0, stream>>>(src, dst, sd, sd + 1, 2, slot, bnd, prepI,
                                              aggb, E, N, /*force=*/0);
        k_final<<<(M + tb - 1) / tb, tb, 0, stream>>>(aggb, sd, sd + 1, 2, gene_idx, slot,
                                                      prepI, W1, b1, W2, b2, f1W, f1b,
                                                      f2W, f2b, out, G, M, npg, N);
    } else {
        // Fallback: R4 layout/path (global atomics)
        float* deg   = ws;                          // N (becomes dinv)
        float* t1o   = ws + (size_t)N;              // N (becomes s)
        float* pO    = ws + 2 * (size_t)N;          // N
        int*   slotO = (int*)(ws + 3 * (size_t)N);  // N
        float* aggbO = ws + 4 * (size_t)N;          // 2*MAXB*M
        float* bndO  = aggbO + (size_t)2 * MAXB * M;
        int*   prepO = (int*)(bndO + 16);

        k_fill_f<<<(2 * N + tb - 1) / tb, tb, 0, stream>>>(deg, 0.0f, 2 * N);
        k_fill_i<<<(N + tb - 1) / tb, tb, 0, stream>>>(slotO, -1, N);
        k_fill_f<<<(2 * MAXB * M + tb - 1) / tb, tb, 0, stream>>>(aggbO, 0.0f, 2 * MAXB * M);
        k_prep<<<1, 64, 0, stream>>>(W1, b1, bndO, prepO);
        k_mark<<<(M + tb - 1) / tb, tb, 0, stream>>>(gene_idx, slotO, G, M, npg, N);
        k_deg<<<(E + tb - 1) / tb, tb, 0, stream>>>(dst, deg, E, N);
        k_dinv_p<<<(N + tb - 1) / tb, tb, 0, stream>>>(x, deg, pO, N);
        k_scatter1<<<(E + tb - 1) / tb, tb, 0, stream>>>(src, dst, pO, t1o, E, N);
        k_s<<<(N + tb - 1) / tb, tb, 0, stream>>>(pO, deg, t1o, N);
        k_agg_atomic<<<2048, tb, 0, stream>>>(src, dst, t1o, deg, 1, slotO, bndO, prepO,
                                              aggbO, E, N, /*force=*/1);
        k_final<<<(M + tb - 1) / tb, tb, 0, stream>>>(aggbO, t1o, deg, 1, gene_idx, slotO,
                                                      prepO, W1, b1, W2, b2, f1W, f1b,
                                                      f2W, f2b, out, G, M, npg, N);
    }
}

// Round 8
// 262.757 us; speedup vs baseline: 4.0047x; 1.0307x over previous
//
#include <hip/hip_runtime.h>

// Fused multi-graph GCN inference (N=320k, E=5.12M, features 1->16->16->8->1).
// Layer-1 collapses to a scalar per node; layer-2 uses the relu-threshold bucket
// trick (agg_j = W1[j]*Sum_act(s*dinv) + b1[j]*Sum_act(dinv), K<=4 fast path).
// Edges counting-sorted by dst-range (1024 nodes/range). R8: per-range passes are
// SUB-BLOCKED (S sub-blocks/range writing partials, merged by N-wide kernels) to
// fix the R=313-blocks-on-256-CUs imbalance + shallow-pipeline latency profile.

#define MAXB 17
#define RS_BITS 10
#define RS (1 << RS_BITS)
#define SRC_BITS 19
#define SRC_MASK ((1u << SRC_BITS) - 1u)
#define CMAX 160                 // compact marked-nodes cap per range
#define PSTRIDE (CMAX * 8)       // partial stride (>= RS for deg/t1 partials: 1280 >= 1024)
#define BK_BT 512                // k_bucket block threads
#define BK_EPT 16
#define BK_TILE (BK_BT * BK_EPT) // 8192

__global__ void k_fill_f(float* __restrict__ w, float v, int n) {
    int i = blockIdx.x * blockDim.x + threadIdx.x;
    if (i < n) w[i] = v;
}
__global__ void k_fill_i(int* __restrict__ w, int v, int n) {
    int i = blockIdx.x * blockDim.x + threadIdx.x;
    if (i < n) w[i] = v;
}

// Single-thread prep: sorted unique relu thresholds + per-bucket active masks.
__global__ void k_prep(const float* __restrict__ W1, const float* __restrict__ b1,
                       float* __restrict__ bnd, int* __restrict__ prepI) {
    if (threadIdx.x != 0 || blockIdx.x != 0) return;
    float t[16]; int type[16]; int pos[16];
    float thr[16]; int nt = 0;
    for (int j = 0; j < 16; j++) {
        float W = W1[j], B = b1[j];
        if (W > 0.f)      { type[j] = 0; t[j] = -B / W; }
        else if (W < 0.f) { type[j] = 1; t[j] = -B / W; }
        else              { type[j] = (B > 0.f) ? 2 : 3; t[j] = 0.f; }
    }
    for (int j = 0; j < 16; j++) {
        if (type[j] > 1) continue;
        float v = t[j];
        int k = 0; while (k < nt && thr[k] < v) k++;
        if (!(k < nt && thr[k] == v)) {
            for (int m = nt; m > k; m--) thr[m] = thr[m - 1];
            thr[k] = v; nt++;
        }
    }
    int K = nt + 1;
    for (int j = 0; j < 16; j++) {
        if (type[j] <= 1) { int k = 0; while (thr[k] != t[j]) k++; pos[j] = k; }
        else pos[j] = 0;
    }
    for (int k = 0; k < 16; k++) bnd[k] = (k < nt) ? thr[k] : 3.4e38f;
    prepI[0] = K;
    for (int k = 0; k < K; k++) {
        unsigned m = 0;
        for (int j = 0; j < 16; j++) {
            bool act;
            if (type[j] == 0)      act = (k >= pos[j] + 1);
            else if (type[j] == 1) act = (k <= pos[j]);
            else                   act = (type[j] == 2);
            if (act) m |= (1u << j);
        }
        prepI[1 + k] = (int)m;
    }
}

__global__ void k_mark(const int* __restrict__ gene_idx, int* __restrict__ slot,
                       int G, int M, int npg, int N) {
    int i = blockIdx.x * blockDim.x + threadIdx.x;
    if (i >= M) return;
    int node = gene_idx[i % G] + (i / G) * npg;
    if ((unsigned)node < (unsigned)N) slot[node] = i;  // race: any winner consistent
}

// Per-range compaction of marked nodes: slot[] becomes cmap in-place.
// cmap: >=0 compact idx (cslot[r*CMAX+idx]=slot), -1 unmarked, <=-2 encodes -(slot+2).
__global__ void k_cmap(int* __restrict__ cm, int* __restrict__ cslot, int* __restrict__ mc,
                       int N, int R) {
    __shared__ int cnt;
    int r = blockIdx.x;
    if (r >= R) return;
    if (threadIdx.x == 0) cnt = 0;
    __syncthreads();
    int b0 = r << RS_BITS;
    for (int i = threadIdx.x; i < RS; i += blockDim.x) {
        int v = b0 + i;
        if (v >= N) continue;
        int sl = cm[v];
        int out;
        if (sl >= 0) {
            int c = atomicAdd(&cnt, 1);
            if (c < CMAX) { cslot[r * CMAX + c] = sl; out = c; }
            else out = -(sl + 2);
        } else out = -1;
        cm[v] = out;
    }
    __syncthreads();
    if (threadIdx.x == 0) mc[r] = min(cnt, CMAX);
}

// ---------- counting sort by dst range ----------

__global__ void k_hist(const int* __restrict__ dst, int* __restrict__ histG,
                       int E, int N, int R) {
    __shared__ int h[512];
    for (int i = threadIdx.x; i < R; i += blockDim.x) h[i] = 0;
    __syncthreads();
    int E4 = E >> 2;
    const int4* d4 = (const int4*)dst;
    for (int e = blockIdx.x * blockDim.x + threadIdx.x; e < E4; e += gridDim.x * blockDim.x) {
        int4 d = d4[e];
        if ((unsigned)d.x < (unsigned)N) atomicAdd(&h[d.x >> RS_BITS], 1);
        if ((unsigned)d.y < (unsigned)N) atomicAdd(&h[d.y >> RS_BITS], 1);
        if ((unsigned)d.z < (unsigned)N) atomicAdd(&h[d.z >> RS_BITS], 1);
        if ((unsigned)d.w < (unsigned)N) atomicAdd(&h[d.w >> RS_BITS], 1);
    }
    for (int e = (E4 << 2) + blockIdx.x * blockDim.x + threadIdx.x; e < E;
         e += gridDim.x * blockDim.x) {
        int d = dst[e];
        if ((unsigned)d < (unsigned)N) atomicAdd(&h[d >> RS_BITS], 1);
    }
    __syncthreads();
    for (int i = threadIdx.x; i < R; i += blockDim.x) {
        int c = h[i];
        if (c) atomicAdd(&histG[i], c);
    }
}

// Exclusive scan of counts PADDED to %4 so every range base is 16B-aligned.
__global__ void k_scan(const int* __restrict__ histG, int* __restrict__ base,
                       int* __restrict__ cursor, int R) {
    __shared__ int a[512];
    int t = threadIdx.x;
    int v = (t < R) ? ((histG[t] + 3) & ~3) : 0;
    a[t] = v;
    __syncthreads();
    for (int off = 1; off < 512; off <<= 1) {
        int add = (t >= off) ? a[t - off] : 0;
        __syncthreads();
        a[t] += add;
        __syncthreads();
    }
    if (t < R) { int ex = a[t] - v; base[t] = ex; cursor[t] = ex; }
}

// Tile-wise bucket scatter with LDS chunk reservation. 625 tiles for balance.
__global__ void __launch_bounds__(BK_BT)
k_bucket(const int* __restrict__ src, const int* __restrict__ dst,
         int* __restrict__ cursorG, unsigned* __restrict__ bucket,
         int E, int N, int R, int cap) {
    __shared__ int cnt[512];
    __shared__ int baseL[512];
    int tile0 = blockIdx.x * BK_TILE;
    for (int i = threadIdx.x; i < R; i += BK_BT) cnt[i] = 0;
    __syncthreads();
    int ds[BK_EPT], ss[BK_EPT];
#pragma unroll
    for (int c = 0; c < 4; c++) {
        int e0 = tile0 + c * (BK_BT * 4) + threadIdx.x * 4;
#pragma unroll
        for (int k = 0; k < 4; k++) {
            int e = e0 + k;
            int idx = c * 4 + k;
            ds[idx] = -1;
            if (e < E) {
                int d = dst[e], s = src[e];
                if ((unsigned)d < (unsigned)N && (unsigned)s < (unsigned)N) {
                    ds[idx] = d; ss[idx] = s;
                    atomicAdd(&cnt[d >> RS_BITS], 1);
                }
            }
        }
    }
    __syncthreads();
    for (int r = threadIdx.x; r < R; r += BK_BT) {
        int c = cnt[r];
        baseL[r] = c > 0 ? atomicAdd(&cursorG[r], c) : 0;
        cnt[r] = 0;
    }
    __syncthreads();
#pragma unroll
    for (int i = 0; i < BK_EPT; i++) {
        int d = ds[i];
        if (d < 0) continue;
        int r = d >> RS_BITS;
        int o = atomicAdd(&cnt[r], 1);
        int idx = baseL[r] + o;
        if ((unsigned)idx < (unsigned)cap)
            bucket[idx] = ((unsigned)(d & (RS - 1)) << SRC_BITS) | (unsigned)ss[i];
    }
}

// ---------- sub-blocked per-range passes (grid = R*S) ----------

// Degree partials: pDeg[(r*S+q)*RS + local]
__global__ void __launch_bounds__(1024)
k_degR2(const unsigned* __restrict__ bucket, const int* __restrict__ base,
        const int* __restrict__ histG, int* __restrict__ pDeg, int cap, int S) {
    __shared__ int degL[RS];
    int r = blockIdx.x / S, q = blockIdx.x % S;
    int nb = base[r];
    int cnt = min(histG[r], cap - nb);
    if (cnt < 0) cnt = 0;
    int lo = (int)(((long long)cnt * q / S) & ~3LL);
    int hi = (q == S - 1) ? cnt : (int)(((long long)cnt * (q + 1) / S) & ~3LL);
    for (int i = threadIdx.x; i < RS; i += blockDim.x) degL[i] = 0;
    __syncthreads();
    for (int i = lo + threadIdx.x * 4; i < hi; i += blockDim.x * 4) {
        uint4 e4 = *(const uint4*)(bucket + nb + i);  // padded: safe
        if (i + 0 < hi) atomicAdd(&degL[e4.x >> SRC_BITS], 1);
        if (i + 1 < hi) atomicAdd(&degL[e4.y >> SRC_BITS], 1);
        if (i + 2 < hi) atomicAdd(&degL[e4.z >> SRC_BITS], 1);
        if (i + 3 < hi) atomicAdd(&degL[e4.w >> SRC_BITS], 1);
    }
    __syncthreads();
    int* out = pDeg + (size_t)(r * S + q) * RS;
    for (int i = threadIdx.x; i < RS; i += blockDim.x) out[i] = degL[i];
}

// Merge deg partials -> dinv (sd[2v+1]) and p[v] = x[v]*dinv.
__global__ void k_dinvp2(const int* __restrict__ pDeg, const float* __restrict__ x,
                         float* __restrict__ sd, float* __restrict__ p, int N, int S) {
    int v = blockIdx.x * blockDim.x + threadIdx.x;
    if (v >= N) return;
    int r = v >> RS_BITS, l = v & (RS - 1);
    int deg = 0;
    for (int q = 0; q < S; q++) deg += pDeg[(size_t)(r * S + q) * RS + l];
    float di = rsqrtf((float)deg + 1.0f);
    sd[2 * v + 1] = di;
    p[v] = x[v] * di;
}

// t1 partials: pT1[(r*S+q)*RS + local] = sum p[src]
__global__ void __launch_bounds__(1024)
k_t1R2(const unsigned* __restrict__ bucket, const int* __restrict__ base,
       const int* __restrict__ histG, const float* __restrict__ p,
       float* __restrict__ pT1, int cap, int S) {
    __shared__ float accL[RS];
    int r = blockIdx.x / S, q = blockIdx.x % S;
    int nb = base[r];
    int cnt = min(histG[r], cap - nb);
    if (cnt < 0) cnt = 0;
    int lo = (int)(((long long)cnt * q / S) & ~3LL);
    int hi = (q == S - 1) ? cnt : (int)(((long long)cnt * (q + 1) / S) & ~3LL);
    for (int i = threadIdx.x; i < RS; i += blockDim.x) accL[i] = 0.f;
    __syncthreads();
    for (int i = lo + threadIdx.x * 4; i < hi; i += blockDim.x * 4) {
        uint4 e4 = *(const uint4*)(bucket + nb + i);
        if (i + 0 < hi) atomicAdd(&accL[e4.x >> SRC_BITS], p[e4.x & SRC_MASK]);
        if (i + 1 < hi) atomicAdd(&accL[e4.y >> SRC_BITS], p[e4.y & SRC_MASK]);
        if (i + 2 < hi) atomicAdd(&accL[e4.z >> SRC_BITS], p[e4.z & SRC_MASK]);
        if (i + 3 < hi) atomicAdd(&accL[e4.w >> SRC_BITS], p[e4.w & SRC_MASK]);
    }
    __syncthreads();
    float* out = pT1 + (size_t)(r * S + q) * RS;
    for (int i = threadIdx.x; i < RS; i += blockDim.x) out[i] = accL[i];
}

// Merge t1 partials -> s[v] = dinv*(t1 + p)  stored in sd[2v].
__global__ void k_s3(const float* __restrict__ pT1, const float* __restrict__ p,
                     float* __restrict__ sd, int N, int S) {
    int v = blockIdx.x * blockDim.x + threadIdx.x;
    if (v >= N) return;
    int r = v >> RS_BITS, l = v & (RS - 1);
    float t1 = 0.f;
    for (int q = 0; q < S; q++) t1 += pT1[(size_t)(r * S + q) * RS + l];
    sd[2 * v] = sd[2 * v + 1] * (t1 + p[v]);
}

// Layer-2 bucket sums, sub-blocked, compact-slot LDS acc + partials.
// Overflow nodes (cmap<=-2) go straight to aggb8 via global atomics (rare).
__global__ void __launch_bounds__(1024)
k_aggS(const unsigned* __restrict__ bucket, const int* __restrict__ base,
       const int* __restrict__ histG, const float* __restrict__ sd,
       const int* __restrict__ cm, const float* __restrict__ bnd,
       const int* __restrict__ prepI, float* __restrict__ pAgg,
       float* __restrict__ aggb8, int N, int cap, int S) {
    __shared__ float acc[PSTRIDE];
    __shared__ int cmapL[RS];
    __shared__ float sB[3];
    __shared__ int sK;
    if (threadIdx.x == 0) sK = prepI[0];
    if (threadIdx.x < 3) sB[threadIdx.x] = bnd[threadIdx.x];
    __syncthreads();
    int K = sK;
    if (K > 4) return;
    int r = blockIdx.x / S, q = blockIdx.x % S;
    int b0 = r << RS_BITS;
    for (int i = threadIdx.x; i < RS; i += blockDim.x) {
        int v = b0 + i;
        cmapL[i] = (v < N) ? cm[v] : -1;
    }
    for (int i = threadIdx.x; i < PSTRIDE; i += blockDim.x) acc[i] = 0.f;
    __syncthreads();
    int nb = base[r];
    int cnt = min(histG[r], cap - nb);
    if (cnt < 0) cnt = 0;
    int lo = (int)(((long long)cnt * q / S) & ~3LL);
    int hi = (q == S - 1) ? cnt : (int)(((long long)cnt * (q + 1) / S) & ~3LL);
    const float2* sd2 = (const float2*)sd;
    for (int i = lo + threadIdx.x * 4; i < hi; i += blockDim.x * 4) {
        uint4 e4 = *(const uint4*)(bucket + nb + i);
        unsigned ee[4] = {e4.x, e4.y, e4.z, e4.w};
#pragma unroll
        for (int k4 = 0; k4 < 4; k4++) {
            if (i + k4 >= hi) break;
            unsigned e = ee[k4];
            int c = cmapL[e >> SRC_BITS];
            if (c == -1) continue;
            float2 v = sd2[e & SRC_MASK];
            int b = 0;
            for (int k = 0; k < K - 1; k++) b += (v.x > sB[k]) ? 1 : 0;
            if (c >= 0) {
                atomicAdd(&acc[c * 8 + 2 * b], v.x * v.y);
                atomicAdd(&acc[c * 8 + 2 * b + 1], v.y);
            } else {
                int sl = -(c + 2);
                atomicAdd(&aggb8[(size_t)sl * 8 + 2 * b], v.x * v.y);
                atomicAdd(&aggb8[(size_t)sl * 8 + 2 * b + 1], v.y);
            }
        }
    }
    __syncthreads();
    float* out = pAgg + (size_t)(r * S + q) * PSTRIDE;
    for (int i = threadIdx.x; i < PSTRIDE; i += blockDim.x) out[i] = acc[i];
}

// Merge agg partials into aggb8 rows (disjoint from overflow-atomic rows).
__global__ void k_aggMerge(const float* __restrict__ pAgg, const int* __restrict__ cslot,
                           const int* __restrict__ mc, float* __restrict__ aggb8,
                           int R, int S) {
    int idx = blockIdx.x * blockDim.x + threadIdx.x;
    int per = CMAX * 8;
    int r = idx / per;
    if (r >= R) return;
    int rem = idx % per;
    int c = rem >> 3, j = rem & 7;
    if (c >= mc[r]) return;
    int sl = cslot[r * CMAX + c];
    if (sl < 0) return;
    float sum = 0.f;
    for (int q = 0; q < S; q++) sum += pAgg[(size_t)(r * S + q) * PSTRIDE + c * 8 + j];
    aggb8[(size_t)sl * 8 + j] = sum;
}

// Zero the wide agg region only when K>4 (rare path).
__global__ void k_fillWide(const int* __restrict__ prepI, float* __restrict__ wide, int n) {
    if (prepI[0] <= 4) return;
    int i = blockIdx.x * blockDim.x + threadIdx.x;
    if (i < n) wide[i] = 0.f;
}

// ---------- generic kernels ----------

__global__ void k_deg(const int* __restrict__ dst, float* __restrict__ deg, int E, int N) {
    int e = blockIdx.x * blockDim.x + threadIdx.x;
    if (e >= E) return;
    int d = dst[e];
    if ((unsigned)d < (unsigned)N) atomicAdd(&deg[d], 1.0f);
}

__global__ void k_dinv_p(const float* __restrict__ x, float* __restrict__ degv,
                         float* __restrict__ p, int N) {
    int v = blockIdx.x * blockDim.x + threadIdx.x;
    if (v < N) {
        float di = rsqrtf(degv[v] + 1.0f);
        degv[v] = di;
        p[v] = x[v] * di;
    }
}

__global__ void k_scatter1(const int* __restrict__ src, const int* __restrict__ dst,
                           const float* __restrict__ p, float* __restrict__ t1, int E, int N) {
    int e = blockIdx.x * blockDim.x + threadIdx.x;
    if (e >= E) return;
    int s = src[e];
    int d = dst[e];
    if ((unsigned)s < (unsigned)N && (unsigned)d < (unsigned)N)
        atomicAdd(&t1[d], p[s]);
}

__global__ void k_s(const float* __restrict__ p, const float* __restrict__ dinv,
                    float* __restrict__ t1, int N) {
    int v = blockIdx.x * blockDim.x + threadIdx.x;
    if (v < N) t1[v] = dinv[v] * (t1[v] + p[v]);
}

// Wide-layout bucket scatter with global atomics.
// mode 0: cm[] holds raw slot (fallback path). mode 1: cm is cmap (decode via cslot).
// force=1: always run. force=0: only when K>4.
__global__ void k_agg_atomic(const int* __restrict__ src, const int* __restrict__ dst,
                             const float* __restrict__ sA, const float* __restrict__ dA,
                             int str, const int* __restrict__ cm, const int* __restrict__ cslot,
                             const float* __restrict__ bnd, const int* __restrict__ prepI,
                             float* __restrict__ wide, int E, int N, int force, int mode) {
    __shared__ float sB[16];
    __shared__ int sK;
    if (threadIdx.x == 0) sK = prepI[0];
    if (threadIdx.x < 16) sB[threadIdx.x] = bnd[threadIdx.x];
    __syncthreads();
    int K = sK;
    if (!force && K <= 4) return;
    int T = K - 1;
    for (int e = blockIdx.x * blockDim.x + threadIdx.x; e < E; e += gridDim.x * blockDim.x) {
        int d = dst[e];
        if ((unsigned)d >= (unsigned)N) continue;
        int c = cm[d];
        int sl;
        if (mode == 0) sl = c;
        else sl = (c >= 0) ? cslot[(d >> RS_BITS) * CMAX + c] : (c <= -2 ? -(c + 2) : -1);
        if (sl < 0) continue;
        int sv = src[e];
        if ((unsigned)sv >= (unsigned)N) continue;
        float sval = sA[(size_t)sv * str];
        float di = dA[(size_t)sv * str];
        int b = 0;
        for (int i = 0; i < T; i++) b += (sval > sB[i]) ? 1 : 0;
        float* row = wide + (size_t)sl * (2 * MAXB) + 2 * b;
        atomicAdd(row, sval * di);
        atomicAdd(row + 1, di);
    }
}

// Head. mode 0: cm = raw slot, rows always wide. mode 1: cmap decode, rows aggb8 if K<=4.
__global__ void k_final(const float* __restrict__ aggb8, const float* __restrict__ wide,
                        const float* __restrict__ sA, const float* __restrict__ dA, int str,
                        const int* __restrict__ gene_idx, const int* __restrict__ cm,
                        const int* __restrict__ cslot, const int* __restrict__ prepI,
                        const float* __restrict__ W1, const float* __restrict__ b1,
                        const float* __restrict__ W2, const float* __restrict__ b2,
                        const float* __restrict__ f1W, const float* __restrict__ f1b,
                        const float* __restrict__ f2W, const float* __restrict__ f2b,
                        float* __restrict__ out, int G, int M, int npg, int N, int mode) {
    __shared__ float sW1[16], sb1[16], sW2[256], sb2[16], sf1[128], sf1b[8], sf2[8], sf2b[1];
    __shared__ int sMask[MAXB], sK;
    for (int i = threadIdx.x; i < 256; i += blockDim.x) sW2[i] = W2[i];
    for (int i = threadIdx.x; i < 128; i += blockDim.x) sf1[i] = f1W[i];
    if (threadIdx.x < 16) { sW1[threadIdx.x] = W1[threadIdx.x]; sb1[threadIdx.x] = b1[threadIdx.x]; sb2[threadIdx.x] = b2[threadIdx.x]; }
    if (threadIdx.x < 8)  { sf1b[threadIdx.x] = f1b[threadIdx.x]; sf2[threadIdx.x] = f2W[threadIdx.x]; }
    if (threadIdx.x == 0) { sf2b[0] = f2b[0]; sK = prepI[0]; }
    if (threadIdx.x < MAXB) sMask[threadIdx.x] = prepI[1 + threadIdx.x];
    __syncthreads();

    int i = blockIdx.x * blockDim.x + threadIdx.x;
    if (i >= M) return;
    int node = gene_idx[i % G] + (i / G) * npg;
    if ((unsigned)node >= (unsigned)N) { out[i] = 0.0f; return; }
    int K = sK;
    int c = cm[node];
    int sl;
    if (mode == 0) sl = c;
    else sl = (c >= 0) ? cslot[(node >> RS_BITS) * CMAX + c] : (c <= -2 ? -(c + 2) : -1);

    float di = dA[(size_t)node * str];
    float sval = sA[(size_t)node * str];

    float bu[MAXB], bw[MAXB];
    if (sl >= 0) {
        const float* row = (mode == 1 && K <= 4) ? (aggb8 + (size_t)sl * 8)
                                                 : (wide + (size_t)sl * (2 * MAXB));
        for (int k = 0; k < K; k++) { bu[k] = row[2 * k]; bw[k] = row[2 * k + 1]; }
    } else {
        for (int k = 0; k < K; k++) { bu[k] = 0.f; bw[k] = 0.f; }
    }

    float a[16];
#pragma unroll
    for (int j = 0; j < 16; j++) {
        float Su = 0.f, Sw = 0.f;
        for (int k = 0; k < K; k++) {
            if ((sMask[k] >> j) & 1) { Su += bu[k]; Sw += bw[k]; }
        }
        float aggj = sW1[j] * Su + sb1[j] * Sw;
        float qself = fmaxf(fmaf(sW1[j], sval, sb1[j]), 0.0f) * di;
        a[j] = di * (aggj + qself);
    }
    float h2[16];
#pragma unroll
    for (int j = 0; j < 16; j++) {
        float acc = sb2[j];
#pragma unroll
        for (int k = 0; k < 16; k++) acc = fmaf(a[k], sW2[k * 16 + j], acc);
        h2[j] = fmaxf(acc, 0.0f);
    }
    float f1[8];
#pragma unroll
    for (int j = 0; j < 8; j++) {
        float acc = sf1b[j];
#pragma unroll
        for (int k = 0; k < 16; k++) acc = fmaf(h2[k], sf1[k * 8 + j], acc);
        f1[j] = fmaxf(acc, 0.0f);
    }
    float o = sf2b[0];
#pragma unroll
    for (int k = 0; k < 8; k++) o = fmaf(f1[k], sf2[k], o);
    out[i] = o;
}

extern "C" void kernel_launch(void* const* d_in, const int* in_sizes, int n_in,
                              void* d_out, int out_size, void* d_ws, size_t ws_size,
                              hipStream_t stream) {
    const float* x        = (const float*)d_in[0];
    const int*   ei       = (const int*)d_in[1];
    const int*   gene_idx = (const int*)d_in[3];
    const float* W1  = (const float*)d_in[5];
    const float* b1  = (const float*)d_in[6];
    const float* W2  = (const float*)d_in[7];
    const float* b2  = (const float*)d_in[8];
    const float* f1W = (const float*)d_in[9];
    const float* f1b = (const float*)d_in[10];
    const float* f2W = (const float*)d_in[11];
    const float* f2b = (const float*)d_in[12];
    float* out = (float*)d_out;

    int N = in_sizes[0];       // 320000
    int E = in_sizes[1] / 2;   // 5120000
    int M = in_sizes[2];       // 32000
    int G = in_sizes[3];       // 1000
    int npg = (int)(((long long)N * (long long)G) / (long long)M);

    const int* src = ei;
    const int* dst = ei + E;

    int R = (N + RS - 1) >> RS_BITS;
    int cap = E + 4 * R + 4;
    const int tb = 256;

    // New-path layout (4B units):
    float* ws = (float*)d_ws;
    size_t off = 0;
    float*    sd     = ws + off;              off += (size_t)2 * N;  // (s,dinv) interleaved
    int*      cm     = (int*)(ws + off);      off += (size_t)N;      // slot -> cmap in place
    float*    p      = ws + off;              off += (size_t)N;
    float*    aggb8  = ws + off;              off += (size_t)8 * M;
    unsigned* bucket = (unsigned*)(ws + off); off += (size_t)cap;    // wide-agg overlay if K>4
    float*    wide   = (float*)bucket;
    int*      cslot  = (int*)(ws + off);      off += (size_t)R * CMAX;
    int*      mc     = (int*)(ws + off);      off += (size_t)R;
    int*      histG  = (int*)(ws + off);      off += (size_t)R;
    int*      baseA  = (int*)(ws + off);      off += (size_t)R;
    int*      cursor = (int*)(ws + off);      off += (size_t)R;
    float*    bnd    = ws + off;              off += 16;
    int*      prepI  = (int*)(ws + off);      off += 20;
    size_t base_need = off;

    // Pick largest S in {4,2,1} that fits: partial = R*S*PSTRIDE floats.
    int S = 4;
    while (S > 1 && (base_need + (size_t)R * S * PSTRIDE) * 4 > ws_size) S >>= 1;
    float* partial = ws + base_need;
    int*   partialI = (int*)partial;
    size_t need = (base_need + (size_t)R * S * PSTRIDE) * 4;

    bool use_new = (need <= ws_size) && (N < (1 << SRC_BITS)) && (R <= 512) &&
                   ((size_t)cap * 4 >= (size_t)2 * MAXB * M * 4);

    if (use_new) {
        int BTr = (S == 1) ? 1024 : 256;  // S=1: fall back to fat blocks for occupancy
        k_fill_i<<<(N + tb - 1) / tb, tb, 0, stream>>>(cm, -1, N);
        k_fill_i<<<(R + tb - 1) / tb, tb, 0, stream>>>(histG, 0, R);
        k_prep<<<1, 64, 0, stream>>>(W1, b1, bnd, prepI);
        k_mark<<<(M + tb - 1) / tb, tb, 0, stream>>>(gene_idx, cm, G, M, npg, N);
        k_cmap<<<R, tb, 0, stream>>>(cm, cslot, mc, N, R);
        k_hist<<<512, tb, 0, stream>>>(dst, histG, E, N, R);
        k_scan<<<1, 512, 0, stream>>>(histG, baseA, cursor, R);
        int ntiles = (E + BK_TILE - 1) / BK_TILE;
        k_bucket<<<ntiles, BK_BT, 0, stream>>>(src, dst, cursor, bucket, E, N, R, cap);
        k_degR2<<<R * S, BTr, 0, stream>>>(bucket, baseA, histG, partialI, cap, S);
        k_dinvp2<<<(N + tb - 1) / tb, tb, 0, stream>>>(partialI, x, sd, p, N, S);
        k_t1R2<<<R * S, BTr, 0, stream>>>(bucket, baseA, histG, p, partial, cap, S);
        k_s3<<<(N + tb - 1) / tb, tb, 0, stream>>>(partial, p, sd, N, S);
        k_fill_f<<<(8 * M + tb - 1) / tb, tb, 0, stream>>>(aggb8, 0.0f, 8 * M);
        k_aggS<<<R * S, BTr, 0, stream>>>(bucket, baseA, histG, sd, cm, bnd, prepI,
                                          partial, aggb8, N, cap, S);
        k_aggMerge<<<(R * CMAX * 8 + tb - 1) / tb, tb, 0, stream>>>(partial, cslot, mc,
                                                                    aggb8, R, S);
        int wn = 2 * MAXB * M;
        k_fillWide<<<(wn + tb - 1) / tb, tb, 0, stream>>>(prepI, wide, wn);
        k_agg_atomic<<<2048, tb, 0, stream>>>(src, dst, sd, sd + 1, 2, cm, cslot, bnd,
                                              prepI, wide, E, N, /*force=*/0, /*mode=*/1);
        k_final<<<(M + tb - 1) / tb, tb, 0, stream>>>(aggb8, wide, sd, sd + 1, 2, gene_idx,
                                                      cm, cslot, prepI, W1, b1, W2, b2,
                                                      f1W, f1b, f2W, f2b, out, G, M, npg, N,
                                                      /*mode=*/1);
    } else {
        // Fallback: global-atomic path, wide layout.
        float* deg   = ws;
        float* t1o   = ws + (size_t)N;
        float* pO    = ws + 2 * (size_t)N;
        int*   slotO = (int*)(ws + 3 * (size_t)N);
        float* wideO = ws + 4 * (size_t)N;
        float* bndO  = wideO + (size_t)2 * MAXB * M;
        int*   prepO = (int*)(bndO + 16);

        k_fill_f<<<(2 * N + tb - 1) / tb, tb, 0, stream>>>(deg, 0.0f, 2 * N);
        k_fill_i<<<(N + tb - 1) / tb, tb, 0, stream>>>(slotO, -1, N);
        k_fill_f<<<(2 * MAXB * M + tb - 1) / tb, tb, 0, stream>>>(wideO, 0.0f, 2 * MAXB * M);
        k_prep<<<1, 64, 0, stream>>>(W1, b1, bndO, prepO);
        k_mark<<<(M + tb - 1) / tb, tb, 0, stream>>>(gene_idx, slotO, G, M, npg, N);
        k_deg<<<(E + tb - 1) / tb, tb, 0, stream>>>(dst, deg, E, N);
        k_dinv_p<<<(N + tb - 1) / tb, tb, 0, stream>>>(x, deg, pO, N);
        k_scatter1<<<(E + tb - 1) / tb, tb, 0, stream>>>(src, dst, pO, t1o, E, N);
        k_s<<<(N + tb - 1) / tb, tb, 0, stream>>>(pO, deg, t1o, N);
        k_agg_atomic<<<2048, tb, 0, stream>>>(src, dst, t1o, deg, 1, slotO, (int*)0, bndO,
                                              prepO, wideO, E, N, /*force=*/1, /*mode=*/0);
        k_final<<<(M + tb - 1) / tb, tb, 0, stream>>>((float*)0, wideO, t1o, deg, 1, gene_idx,
                                                      slotO, (int*)0, prepO, W1, b1, W2, b2,
                                                      f1W, f1b, f2W, f2b, out, G, M, npg, N,
                                                      /*mode=*/0);
    }
}